// Round 1
// baseline (2882.258 us; speedup 1.0000x reference)
//
#include <hip/hip_runtime.h>
#include <hip/hip_bf16.h>

__device__ __forceinline__ float bf_lo(unsigned v) { return __uint_as_float(v << 16); }
__device__ __forceinline__ float bf_hi(unsigned v) { return __uint_as_float(v & 0xFFFF0000u); }
__device__ __forceinline__ float prelu(float v, float a) { return v >= 0.0f ? v : v * a; }

#define SM_TOTAL 18896
#define X_OFF    8464

__global__ __launch_bounds__(256, 2)
void onet_kernel(const float* __restrict__ gin,
                 const float* __restrict__ w1, const float* __restrict__ b1, const float* __restrict__ a1,
                 const float* __restrict__ w2, const float* __restrict__ b2, const float* __restrict__ a2,
                 const float* __restrict__ w3, const float* __restrict__ b3, const float* __restrict__ a3,
                 const float* __restrict__ w4, const float* __restrict__ b4, const float* __restrict__ a4,
                 const float* __restrict__ w5, const float* __restrict__ b5, const float* __restrict__ a5,
                 const float* __restrict__ wcls, const float* __restrict__ bcls,
                 const float* __restrict__ wbox, const float* __restrict__ bbox,
                 const float* __restrict__ wpts, const float* __restrict__ bpts,
                 float* __restrict__ out, int nimg)
{
  // LDS layout (floats):
  //  [0,8464)        pool1 bf16 [23][23][32]  (later reused: c3 [0,4096), pool3 [4096,5120),
  //                                            vec1152 [5120,6272), d5 [6272,6528), zz [6528,6544))
  //  [8464,18896)    region X: stage A: in_s bf16 [48][3][52] (3744 fl)
  //                            stage B: pool2 fp32 [10][10][64] (6400 fl) + cb2 fp32 [3][21][64] (4032 fl)
  __shared__ __align__(16) float smem[SM_TOTAL];
  const int t = threadIdx.x;
  const int img = blockIdx.x;

  // ---------- Stage A load: input -> in_s[h][ci][w] bf16 (stride 52) ----------
  {
    __hip_bfloat16* in_s = (__hip_bfloat16*)(smem + X_OFF);
    const float* inp = gin + (size_t)img * 6912;
    for (int i = t; i < 6912; i += 256) {
      int h = i / 144;
      int r = i - h * 144;
      int w = r / 3;
      int ci = r - w * 3;
      in_s[(h * 3 + ci) * 52 + w] = __float2bfloat16(inp[i]);
    }
  }
  __syncthreads();

  // ---------- Stage A: conv1(3x3x3->32)+PReLU+pool1(3x3 s2, pad bottom/right) ----------
  // per-thread column strip: thread (c = t&31 channel, p = t>>5): pool cols 3p..3p+2, conv cols 6p..6p+6
  {
    const __hip_bfloat16* in_s = (const __hip_bfloat16*)(smem + X_OFF);
    __hip_bfloat16* pool1 = (__hip_bfloat16*)smem;
    const int c = t & 31;
    const int p = t >> 5;
    const int wbase = 6 * p;
    float wr[27];
    #pragma unroll
    for (int k = 0; k < 27; ++k) wr[k] = w1[k * 32 + c];   // k=(kh*3+kw)*3+ci
    const float bias = b1[c];
    const float al = a1[c];
    const int xmax = 45 - wbase;          // last valid conv col offset (p=7 -> 3)
    float m1[3], m2[3];
    #pragma unroll
    for (int q = 0; q < 3; ++q) { m1[q] = -1e30f; m2[q] = -1e30f; }
    for (int h = 0; h < 46; ++h) {
      float cc[7];
      #pragma unroll
      for (int x = 0; x < 7; ++x) cc[x] = bias;
      #pragma unroll
      for (int kh = 0; kh < 3; ++kh) {
        #pragma unroll
        for (int ci = 0; ci < 3; ++ci) {
          const unsigned* rp = (const unsigned*)(in_s + ((h + kh) * 3 + ci) * 52 + wbase);
          float xv[10];
          #pragma unroll
          for (int k = 0; k < 5; ++k) {
            unsigned v = rp[k];
            xv[2 * k]     = bf_lo(v);
            xv[2 * k + 1] = bf_hi(v);
          }
          #pragma unroll
          for (int kw = 0; kw < 3; ++kw) {
            float wv = wr[(kh * 3 + kw) * 3 + ci];
            #pragma unroll
            for (int x = 0; x < 7; ++x) cc[x] = fmaf(xv[x + kw], wv, cc[x]);
          }
        }
      }
      float cm[3];
      #pragma unroll
      for (int x = 0; x < 7; ++x) {
        float v = prelu(cc[x], al);
        cc[x] = (x <= xmax) ? v : -1e30f;   // mask cols > 45 (and p=7 tail)
      }
      cm[0] = fmaxf(fmaxf(cc[0], cc[1]), cc[2]);
      cm[1] = fmaxf(fmaxf(cc[2], cc[3]), cc[4]);
      cm[2] = fmaxf(fmaxf(cc[4], cc[5]), cc[6]);
      if (h >= 2 && (h & 1) == 0) {
        int r = (h >> 1) - 1;               // pool row finalized by conv rows {h-2,h-1,h}
        #pragma unroll
        for (int q = 0; q < 3; ++q) {
          int col = 3 * p + q;
          if (col < 23) {
            float m = fmaxf(fmaxf(cm[q], m1[q]), m2[q]);
            pool1[(r * 23 + col) * 32 + c] = __float2bfloat16(m);
          }
        }
      }
      #pragma unroll
      for (int q = 0; q < 3; ++q) { m2[q] = m1[q]; m1[q] = cm[q]; }
    }
    // pool row 22: conv rows 44,45 (row 46 is pad)
    #pragma unroll
    for (int q = 0; q < 3; ++q) {
      int col = 3 * p + q;
      if (col < 23) {
        float m = fmaxf(m1[q], m2[q]);
        pool1[(22 * 23 + col) * 32 + c] = __float2bfloat16(m);
      }
    }
  }
  __syncthreads();

  // ---------- Stage B: conv2(3x3x32->64)+PReLU (rolling 3 rows) + pool2(3x3 s2 VALID) ----------
  {
    const __hip_bfloat16* pool1 = (const __hip_bfloat16*)smem;
    float* pool2 = smem + X_OFF;            // [10][10][64]
    float* cb2   = smem + X_OFF + 6400;     // [3][21][64]
    const int c = t & 31;                   // channels c, c+32
    const int p = t >> 5;                   // cols p+8j, j=0..2
    const float bsa = b2[c], bsb = b2[c + 32];
    const float ala = a2[c], alb = a2[c + 32];
    for (int r = 0; r < 10; ++r) {
      int h0 = (r == 0) ? 0 : 2 * r + 1;
      int h1 = 2 * r + 2;
      for (int h = h0; h <= h1; ++h) {
        float acc[3][2];
        #pragma unroll
        for (int j = 0; j < 3; ++j) { acc[j][0] = bsa; acc[j][1] = bsb; }
        for (int cq = 0; cq < 4; ++cq) {    // ci blocks of 8
          #pragma unroll
          for (int kh = 0; kh < 3; ++kh) {
            const __hip_bfloat16* prow = pool1 + ((h + kh) * 23) * 32 + cq * 8;
            uint4 colv[9];
            #pragma unroll
            for (int jj = 0; jj < 3; ++jj) {
              #pragma unroll
              for (int kw = 0; kw < 3; ++kw) {
                int col = p + 8 * jj + kw;
                colv[jj * 3 + kw] = *(const uint4*)(prow + col * 32);
              }
            }
            #pragma unroll
            for (int kw = 0; kw < 3; ++kw) {
              #pragma unroll
              for (int ci = 0; ci < 8; ++ci) {
                const float* wrow = w2 + ((kh * 3 + kw) * 32 + cq * 8 + ci) * 64 + c;
                float wa  = wrow[0];
                float wbv = wrow[32];
                #pragma unroll
                for (int j = 0; j < 3; ++j) {
                  unsigned pr = ((const unsigned*)&colv[j * 3 + kw])[ci >> 1];
                  float x = (ci & 1) ? bf_hi(pr) : bf_lo(pr);
                  acc[j][0] = fmaf(x, wa,  acc[j][0]);
                  acc[j][1] = fmaf(x, wbv, acc[j][1]);
                }
              }
            }
          }
        }
        float* crow = cb2 + (h % 3) * 21 * 64;
        #pragma unroll
        for (int j = 0; j < 3; ++j) {
          int w = p + 8 * j;
          if (w < 21) {
            crow[w * 64 + c]      = prelu(acc[j][0], ala);
            crow[w * 64 + c + 32] = prelu(acc[j][1], alb);
          }
        }
      }
      __syncthreads();
      #pragma unroll
      for (int jj = 0; jj < 2; ++jj) {
        int w = p + 8 * jj;
        if (w < 10) {
          float ma = -1e30f, mb = -1e30f;
          #pragma unroll
          for (int kh = 0; kh < 3; ++kh) {
            const float* cr = cb2 + ((2 * r + kh) % 3) * 21 * 64 + (2 * w) * 64;
            #pragma unroll
            for (int kw = 0; kw < 3; ++kw) {
              ma = fmaxf(ma, cr[kw * 64 + c]);
              mb = fmaxf(mb, cr[kw * 64 + c + 32]);
            }
          }
          pool2[(r * 10 + w) * 64 + c]      = ma;
          pool2[(r * 10 + w) * 64 + c + 32] = mb;
        }
      }
      __syncthreads();
    }
  }

  // ---------- Stage C: conv3(3x3x64->64)+PReLU -> c3 [8][8][64]; pool3(2x2 s2) ----------
  {
    const float* pool2c = smem + X_OFF;
    float* c3 = smem;                       // pool1 region is dead now
    const int c = t & 31;
    const int p = t >> 5;                   // output column p, all 8 rows
    float acc[8][2];
    const float b3a = b3[c], b3b = b3[c + 32];
    #pragma unroll
    for (int i = 0; i < 8; ++i) { acc[i][0] = b3a; acc[i][1] = b3b; }
    for (int kh = 0; kh < 3; ++kh) {
      for (int kw = 0; kw < 3; ++kw) {
        for (int cq = 0; cq < 16; ++cq) {   // 4 ci per block
          float4 xv[8];
          #pragma unroll
          for (int i = 0; i < 8; ++i)
            xv[i] = *(const float4*)(pool2c + ((kh + i) * 10 + (p + kw)) * 64 + cq * 4);
          #pragma unroll
          for (int ci = 0; ci < 4; ++ci) {
            const float* wrow = w3 + ((kh * 3 + kw) * 64 + cq * 4 + ci) * 64 + c;
            float wa  = wrow[0];
            float wbv = wrow[32];
            #pragma unroll
            for (int i = 0; i < 8; ++i) {
              float x = ((const float*)&xv[i])[ci];
              acc[i][0] = fmaf(x, wa,  acc[i][0]);
              acc[i][1] = fmaf(x, wbv, acc[i][1]);
            }
          }
        }
      }
    }
    const float a3a = a3[c], a3b = a3[c + 32];
    #pragma unroll
    for (int i = 0; i < 8; ++i) {
      c3[(i * 8 + p) * 64 + c]      = prelu(acc[i][0], a3a);
      c3[(i * 8 + p) * 64 + c + 32] = prelu(acc[i][1], a3b);
    }
  }
  __syncthreads();
  {
    const float* c3 = smem;
    float* pool3 = smem + 4096;             // [4][4][64]
    const int c = t & 31;
    const int p = t >> 5;
    #pragma unroll
    for (int j = 0; j < 2; ++j) {
      int pos = p + 8 * j;
      int pi = pos >> 2, pj = pos & 3;
      #pragma unroll
      for (int e = 0; e < 2; ++e) {
        int ch = c + 32 * e;
        float m = fmaxf(
            fmaxf(c3[((2 * pi) * 8 + 2 * pj) * 64 + ch],     c3[((2 * pi) * 8 + 2 * pj + 1) * 64 + ch]),
            fmaxf(c3[((2 * pi + 1) * 8 + 2 * pj) * 64 + ch], c3[((2 * pi + 1) * 8 + 2 * pj + 1) * 64 + ch]));
        pool3[(pi * 4 + pj) * 64 + ch] = m;
      }
    }
  }
  __syncthreads();

  // ---------- Stage D: conv4(2x2x64->128)+PReLU -> vec[c*9 + w*3 + h] (permute 3,2,1 flatten) ----------
  {
    const float* pool3 = smem + 4096;
    float* vec = smem + 5120;               // [1152]
    const int c = t & 127;
    const int p = t >> 7;                   // pos = p + 2j
    float acc[5];
    const float b4c = b4[c];
    #pragma unroll
    for (int j = 0; j < 5; ++j) acc[j] = b4c;
    for (int kh = 0; kh < 2; ++kh) {
      for (int kw = 0; kw < 2; ++kw) {
        for (int cq = 0; cq < 16; ++cq) {
          float4 xv[5];
          #pragma unroll
          for (int j = 0; j < 5; ++j) {
            int pos = p + 2 * j;
            if (pos < 9) {
              int hh = pos / 3, ww = pos - hh * 3;
              xv[j] = *(const float4*)(pool3 + ((hh + kh) * 4 + (ww + kw)) * 64 + cq * 4);
            }
          }
          #pragma unroll
          for (int ci = 0; ci < 4; ++ci) {
            float wv = w4[((kh * 2 + kw) * 64 + cq * 4 + ci) * 128 + c];
            #pragma unroll
            for (int j = 0; j < 5; ++j) {
              int pos = p + 2 * j;
              if (pos < 9)
                acc[j] = fmaf(((const float*)&xv[j])[ci], wv, acc[j]);
            }
          }
        }
      }
    }
    const float a4c = a4[c];
    #pragma unroll
    for (int j = 0; j < 5; ++j) {
      int pos = p + 2 * j;
      if (pos < 9) {
        int hh = pos / 3, ww = pos - hh * 3;
        vec[c * 9 + ww * 3 + hh] = prelu(acc[j], a4c);
      }
    }
  }
  __syncthreads();

  // ---------- Stage E: dense5 (1152->256) + PReLU ----------
  {
    const float* vec = smem + 5120;
    float* d5 = smem + 6272;
    const int jj = t;
    float acc0 = 0.f, acc1 = 0.f, acc2 = 0.f, acc3 = 0.f;
    for (int k = 0; k < 1152; k += 4) {
      float4 xv = *(const float4*)(vec + k);
      acc0 = fmaf(xv.x, w5[(k    ) * 256 + jj], acc0);
      acc1 = fmaf(xv.y, w5[(k + 1) * 256 + jj], acc1);
      acc2 = fmaf(xv.z, w5[(k + 2) * 256 + jj], acc2);
      acc3 = fmaf(xv.w, w5[(k + 3) * 256 + jj], acc3);
    }
    float v = (acc0 + acc1) + (acc2 + acc3) + b5[jj];
    d5[jj] = prelu(v, a5[jj]);
  }
  __syncthreads();

  // ---------- Heads: 16 outputs, 16 lanes each ----------
  {
    const float* d5 = smem + 6272;
    float* zz = smem + 6528;
    const int o = t >> 4, s = t & 15;
    float pa = 0.f;
    if (o < 2) {
      for (int k = s; k < 256; k += 16) pa += d5[k] * wcls[k * 2 + o];
    } else if (o < 6) {
      int oc = o - 2;
      for (int k = s; k < 256; k += 16) pa += d5[k] * wbox[k * 4 + oc];
    } else {
      int oc = o - 6;
      for (int k = s; k < 256; k += 16) pa += d5[k] * wpts[k * 10 + oc];
    }
    pa += __shfl_xor(pa, 1);
    pa += __shfl_xor(pa, 2);
    pa += __shfl_xor(pa, 4);
    pa += __shfl_xor(pa, 8);
    if (s == 0) {
      float bias = (o < 2) ? bcls[o] : (o < 6) ? bbox[o - 2] : bpts[o - 6];
      zz[o] = pa + bias;
    }
  }
  __syncthreads();
  if (t < 16) {
    const float* zz = smem + 6528;
    int o = t;
    if (o < 2) {
      float z0 = zz[0], z1 = zz[1];
      float m = fmaxf(z0, z1);
      float e0 = __expf(z0 - m), e1 = __expf(z1 - m);
      out[(size_t)img * 2 + o] = ((o == 0) ? e0 : e1) / (e0 + e1);
    } else if (o < 6) {
      out[(size_t)nimg * 2 + (size_t)img * 4 + (o - 2)] = zz[o];
    } else {
      out[(size_t)nimg * 6 + (size_t)img * 10 + (o - 6)] = zz[o];
    }
  }
}

extern "C" void kernel_launch(void* const* d_in, const int* in_sizes, int n_in,
                              void* d_out, int out_size, void* d_ws, size_t ws_size,
                              hipStream_t stream) {
  (void)n_in; (void)out_size; (void)d_ws; (void)ws_size;
  const float* gin  = (const float*)d_in[0];
  const float* w1   = (const float*)d_in[1];
  const float* b1   = (const float*)d_in[2];
  const float* a1   = (const float*)d_in[3];
  const float* w2   = (const float*)d_in[4];
  const float* b2   = (const float*)d_in[5];
  const float* a2   = (const float*)d_in[6];
  const float* w3   = (const float*)d_in[7];
  const float* b3   = (const float*)d_in[8];
  const float* a3   = (const float*)d_in[9];
  const float* w4   = (const float*)d_in[10];
  const float* b4   = (const float*)d_in[11];
  const float* a4   = (const float*)d_in[12];
  const float* w5   = (const float*)d_in[13];
  const float* b5   = (const float*)d_in[14];
  const float* a5   = (const float*)d_in[15];
  const float* wcls = (const float*)d_in[16];
  const float* bcls = (const float*)d_in[17];
  const float* wbox = (const float*)d_in[18];
  const float* bbox = (const float*)d_in[19];
  const float* wpts = (const float*)d_in[20];
  const float* bpts = (const float*)d_in[21];
  float* out = (float*)d_out;
  const int nimg = in_sizes[0] / 6912;   // 4096
  onet_kernel<<<nimg, 256, 0, stream>>>(gin, w1, b1, a1, w2, b2, a2, w3, b3, a3,
                                        w4, b4, a4, w5, b5, a5,
                                        wcls, bcls, wbox, bbox, wpts, bpts, out, nimg);
}

// Round 2
// 1024.668 us; speedup vs baseline: 2.8129x; 2.8129x over previous
//
#include <hip/hip_runtime.h>
#include <hip/hip_bf16.h>

typedef __attribute__((ext_vector_type(8))) short short8;   // 8 bf16 = 4 VGPRs (MFMA A/B frag)
typedef __attribute__((ext_vector_type(4))) float f32x4;    // MFMA C/D frag

__device__ __forceinline__ float bf_lo(unsigned v) { return __uint_as_float(v << 16); }
__device__ __forceinline__ float bf_hi(unsigned v) { return __uint_as_float(v & 0xFFFF0000u); }
__device__ __forceinline__ float prelu(float v, float a) { return v >= 0.0f ? v : v * a; }

// LDS layout (float offsets)
#define P1F   0       // pool1 bf16 [529 pos][40 ch pad]  (10580 fl)  -- stride 80B => conflict-free b128
#define INF   10580   // stage-A input bf16 [48][3][52]   (3744 fl)
#define CB2F  10580   // conv2 band bf16 [3][21][64]      (2016 fl)   (in_s dead)
#define P2F   12596   // pool2 bf16 [100 pos][72 ch pad]  (3600 fl)
#define C3F   0       // conv3 out fp32 [64][64]          (4096 fl)   (pool1 dead)
#define P3F   4096    // pool3 fp32 [16][64]              (1024 fl)
#define VECF  5120    // flatten fp32 [1152]
#define D5F   6272    // dense5 out fp32 [256]
#define ZZF   6528    // head logits [16]
#define SMF   16196   // 64,784 B -> 2 blocks/CU

// d_ws layout (bf16 elements): w2t[9][64co][32k] | w3t[9][2cg][64co][32k] | w5t[256jj][1152k]
#define W2T_OFF 0
#define W3T_OFF 18432
#define W5T_OFF 55296
#define WS_ELEMS 350208

__global__ void prep_weights(const float* __restrict__ w2, const float* __restrict__ w3,
                             const float* __restrict__ w5, __hip_bfloat16* __restrict__ ws) {
  int i = blockIdx.x * 256 + threadIdx.x;
  if (i < 18432) {
    int khkw = i >> 11, rem = i & 2047, co = rem >> 5, k = rem & 31;
    ws[i] = __float2bfloat16(w2[(khkw * 32 + k) * 64 + co]);
  } else if (i < 55296) {
    int j = i - 18432;
    int khkwcg = j >> 11, rem = j & 2047, co = rem >> 5, k = rem & 31;
    int khkw = khkwcg >> 1, cg = khkwcg & 1;
    ws[i] = __float2bfloat16(w3[(khkw * 64 + cg * 32 + k) * 64 + co]);
  } else if (i < WS_ELEMS) {
    int j = i - 55296;
    int jj = j / 1152, k = j - jj * 1152;
    ws[i] = __float2bfloat16(w5[k * 256 + jj]);
  }
}

__global__ __launch_bounds__(256, 2)
void onet_kernel(const float* __restrict__ gin,
                 const float* __restrict__ w1, const float* __restrict__ b1, const float* __restrict__ a1,
                 const float* __restrict__ b2, const float* __restrict__ a2,
                 const float* __restrict__ b3, const float* __restrict__ a3,
                 const float* __restrict__ w4, const float* __restrict__ b4, const float* __restrict__ a4,
                 const float* __restrict__ b5, const float* __restrict__ a5,
                 const float* __restrict__ wcls, const float* __restrict__ bcls,
                 const float* __restrict__ wbox, const float* __restrict__ bbox,
                 const float* __restrict__ wpts, const float* __restrict__ bpts,
                 const __hip_bfloat16* __restrict__ ws,
                 float* __restrict__ out, int nimg)
{
  __shared__ __align__(16) float smem[SMF];
  const int t = threadIdx.x;
  const int img = blockIdx.x;
  const __hip_bfloat16* w2t = ws + W2T_OFF;
  const __hip_bfloat16* w3t = ws + W3T_OFF;
  const __hip_bfloat16* w5t = ws + W5T_OFF;

  // ---------- Stage A load: input -> in_s[h][ci][w] bf16 (stride 52) ----------
  {
    __hip_bfloat16* in_s = (__hip_bfloat16*)(smem + INF);
    const float* inp = gin + (size_t)img * 6912;
    for (int i = t; i < 6912; i += 256) {
      int h = i / 144;
      int r = i - h * 144;
      int w = r / 3;
      int ci = r - w * 3;
      in_s[(h * 3 + ci) * 52 + w] = __float2bfloat16(inp[i]);
    }
  }
  __syncthreads();

  // ---------- Stage A: conv1(3x3x3->32)+PReLU+pool1 (vector fp32) ----------
  {
    const __hip_bfloat16* in_s = (const __hip_bfloat16*)(smem + INF);
    __hip_bfloat16* pool1 = (__hip_bfloat16*)(smem + P1F);   // [pos][40]
    const int c = t & 31;
    const int p = t >> 5;
    const int wbase = 6 * p;
    float wr[27];
    #pragma unroll
    for (int k = 0; k < 27; ++k) wr[k] = w1[k * 32 + c];
    const float bias = b1[c];
    const float al = a1[c];
    const int xmax = 45 - wbase;
    float m1[3], m2[3];
    #pragma unroll
    for (int q = 0; q < 3; ++q) { m1[q] = -1e30f; m2[q] = -1e30f; }
    for (int h = 0; h < 46; ++h) {
      float cc[7];
      #pragma unroll
      for (int x = 0; x < 7; ++x) cc[x] = bias;
      #pragma unroll
      for (int kh = 0; kh < 3; ++kh) {
        #pragma unroll
        for (int ci = 0; ci < 3; ++ci) {
          const unsigned* rp = (const unsigned*)(in_s + ((h + kh) * 3 + ci) * 52 + wbase);
          float xv[10];
          #pragma unroll
          for (int k = 0; k < 5; ++k) {
            unsigned v = rp[k];
            xv[2 * k]     = bf_lo(v);
            xv[2 * k + 1] = bf_hi(v);
          }
          #pragma unroll
          for (int kw = 0; kw < 3; ++kw) {
            float wv = wr[(kh * 3 + kw) * 3 + ci];
            #pragma unroll
            for (int x = 0; x < 7; ++x) cc[x] = fmaf(xv[x + kw], wv, cc[x]);
          }
        }
      }
      float cm[3];
      #pragma unroll
      for (int x = 0; x < 7; ++x) {
        float v = prelu(cc[x], al);
        cc[x] = (x <= xmax) ? v : -1e30f;
      }
      cm[0] = fmaxf(fmaxf(cc[0], cc[1]), cc[2]);
      cm[1] = fmaxf(fmaxf(cc[2], cc[3]), cc[4]);
      cm[2] = fmaxf(fmaxf(cc[4], cc[5]), cc[6]);
      if (h >= 2 && (h & 1) == 0) {
        int r = (h >> 1) - 1;
        #pragma unroll
        for (int q = 0; q < 3; ++q) {
          int col = 3 * p + q;
          if (col < 23) {
            float m = fmaxf(fmaxf(cm[q], m1[q]), m2[q]);
            pool1[(r * 23 + col) * 40 + c] = __float2bfloat16(m);
          }
        }
      }
      #pragma unroll
      for (int q = 0; q < 3; ++q) { m2[q] = m1[q]; m1[q] = cm[q]; }
    }
    #pragma unroll
    for (int q = 0; q < 3; ++q) {
      int col = 3 * p + q;
      if (col < 23) {
        float m = fmaxf(m1[q], m2[q]);
        pool1[(22 * 23 + col) * 40 + c] = __float2bfloat16(m);
      }
    }
  }
  __syncthreads();

  // ---------- Stage B: conv2 (3x3x32->64) via MFMA + pool2 ----------
  // Band per pool row r: conv rows 2r..2r+2 (recompute overlap), 63 positions -> 4 M-tiles.
  // Wave owns M-tile; B-frags (9 khkw x 4 ntile) cached in 144 VGPRs per image.
  {
    const __hip_bfloat16* pool1b = (const __hip_bfloat16*)(smem + P1F);
    __hip_bfloat16* cb2 = (__hip_bfloat16*)(smem + CB2F);    // [3][21][64]
    __hip_bfloat16* pool2 = (__hip_bfloat16*)(smem + P2F);   // [100][72]
    const int wv = t >> 6;       // wave id = M-tile
    const int l  = t & 63;
    const int lr = l & 15;       // A-row-in-tile / C col
    const int lg = l >> 4;       // k group / C row group
    short8 bfr[9][4];
    #pragma unroll
    for (int khkw = 0; khkw < 9; ++khkw)
      #pragma unroll
      for (int nt = 0; nt < 4; ++nt)
        bfr[khkw][nt] = *(const short8*)(w2t + ((khkw * 64 + nt * 16 + lr) * 32 + 8 * lg));
    int mA = wv * 16 + lr; if (mA > 62) mA = 62;
    const int krA = mA / 21, owA = mA - krA * 21;
    int mc[4], krc[4], owc[4];
    #pragma unroll
    for (int reg = 0; reg < 4; ++reg) {
      mc[reg] = wv * 16 + lg * 4 + reg;
      krc[reg] = mc[reg] / 21;
      owc[reg] = mc[reg] - krc[reg] * 21;
    }
    float bsn[4], alv[4];
    #pragma unroll
    for (int nt = 0; nt < 4; ++nt) { bsn[nt] = b2[nt * 16 + lr]; alv[nt] = a2[nt * 16 + lr]; }

    for (int r = 0; r < 10; ++r) {
      const int posA = (2 * r + krA) * 23 + owA;
      f32x4 acc[4];
      #pragma unroll
      for (int nt = 0; nt < 4; ++nt) acc[nt] = (f32x4){bsn[nt], bsn[nt], bsn[nt], bsn[nt]};
      #pragma unroll
      for (int kh = 0; kh < 3; ++kh)
        #pragma unroll
        for (int kw = 0; kw < 3; ++kw) {
          short8 af = *(const short8*)(pool1b + (posA + kh * 23 + kw) * 40 + 8 * lg);
          #pragma unroll
          for (int nt = 0; nt < 4; ++nt)
            acc[nt] = __builtin_amdgcn_mfma_f32_16x16x32_bf16(af, bfr[kh * 3 + kw][nt], acc[nt], 0, 0, 0);
        }
      #pragma unroll
      for (int nt = 0; nt < 4; ++nt)
        #pragma unroll
        for (int reg = 0; reg < 4; ++reg)
          if (mc[reg] < 63)
            cb2[(krc[reg] * 21 + owc[reg]) * 64 + nt * 16 + lr] =
                __float2bfloat16(prelu(acc[nt][reg], alv[nt]));
      __syncthreads();
      {
        const int ch = t & 63;
        #pragma unroll
        for (int jj = 0; jj < 3; ++jj) {
          int w = (t >> 6) + 4 * jj;
          if (w < 10) {
            float m = -1e30f;
            #pragma unroll
            for (int kh = 0; kh < 3; ++kh)
              #pragma unroll
              for (int kw = 0; kw < 3; ++kw)
                m = fmaxf(m, __bfloat162float(cb2[(kh * 21 + 2 * w + kw) * 64 + ch]));
            pool2[(r * 10 + w) * 72 + ch] = __float2bfloat16(m);
          }
        }
      }
      __syncthreads();
    }
  }

  // ---------- Stage C: conv3 (3x3x64->64) via MFMA -> c3 fp32 [64][64] ----------
  // Wave owns N-tile (16 ch); 18 B-frags (9 khkw x 2 cg) in 72 VGPRs.
  {
    const __hip_bfloat16* pool2b = (const __hip_bfloat16*)(smem + P2F);
    float* c3 = smem + C3F;
    const int nt = t >> 6;
    const int l  = t & 63;
    const int lr = l & 15;
    const int lg = l >> 4;
    short8 bfr[9][2];
    #pragma unroll
    for (int khkw = 0; khkw < 9; ++khkw)
      #pragma unroll
      for (int cg = 0; cg < 2; ++cg)
        bfr[khkw][cg] = *(const short8*)(w3t + (((khkw * 2 + cg) * 64 + nt * 16 + lr) * 32 + 8 * lg));
    const float bs = b3[nt * 16 + lr], al = a3[nt * 16 + lr];
    #pragma unroll
    for (int mt = 0; mt < 4; ++mt) {
      const int mA = mt * 16 + lr;
      const int ohA = mA >> 3, owA = mA & 7;
      f32x4 acc = (f32x4){bs, bs, bs, bs};
      #pragma unroll
      for (int kh = 0; kh < 3; ++kh)
        #pragma unroll
        for (int kw = 0; kw < 3; ++kw)
          #pragma unroll
          for (int cg = 0; cg < 2; ++cg) {
            short8 af = *(const short8*)(pool2b + ((ohA + kh) * 10 + owA + kw) * 72 + cg * 32 + 8 * lg);
            acc = __builtin_amdgcn_mfma_f32_16x16x32_bf16(af, bfr[kh * 3 + kw][cg], acc, 0, 0, 0);
          }
      #pragma unroll
      for (int reg = 0; reg < 4; ++reg) {
        int m = mt * 16 + lg * 4 + reg;
        c3[m * 64 + nt * 16 + lr] = prelu(acc[reg], al);
      }
    }
  }
  __syncthreads();

  // ---------- pool3 (2x2 s2) ----------
  {
    const float* c3 = smem + C3F;
    float* pool3 = smem + P3F;
    const int c = t & 31;
    const int p = t >> 5;
    #pragma unroll
    for (int j = 0; j < 2; ++j) {
      int pos = p + 8 * j;
      int pi = pos >> 2, pj = pos & 3;
      #pragma unroll
      for (int e = 0; e < 2; ++e) {
        int ch = c + 32 * e;
        float m = fmaxf(
            fmaxf(c3[((2 * pi) * 8 + 2 * pj) * 64 + ch],     c3[((2 * pi) * 8 + 2 * pj + 1) * 64 + ch]),
            fmaxf(c3[((2 * pi + 1) * 8 + 2 * pj) * 64 + ch], c3[((2 * pi + 1) * 8 + 2 * pj + 1) * 64 + ch]));
        pool3[(pi * 4 + pj) * 64 + ch] = m;
      }
    }
  }
  __syncthreads();

  // ---------- Stage D: conv4 (2x2x64->128)+PReLU -> vec (vector) ----------
  {
    const float* pool3 = smem + P3F;
    float* vec = smem + VECF;
    const int c = t & 127;
    const int p = t >> 7;
    float acc[5];
    const float b4c = b4[c];
    #pragma unroll
    for (int j = 0; j < 5; ++j) acc[j] = b4c;
    for (int kh = 0; kh < 2; ++kh) {
      for (int kw = 0; kw < 2; ++kw) {
        for (int cq = 0; cq < 16; ++cq) {
          float4 xv[5];
          #pragma unroll
          for (int j = 0; j < 5; ++j) {
            int pos = p + 2 * j;
            if (pos < 9) {
              int hh = pos / 3, ww = pos - hh * 3;
              xv[j] = *(const float4*)(pool3 + ((hh + kh) * 4 + (ww + kw)) * 64 + cq * 4);
            }
          }
          #pragma unroll
          for (int ci = 0; ci < 4; ++ci) {
            float wv = w4[((kh * 2 + kw) * 64 + cq * 4 + ci) * 128 + c];
            #pragma unroll
            for (int j = 0; j < 5; ++j) {
              int pos = p + 2 * j;
              if (pos < 9)
                acc[j] = fmaf(((const float*)&xv[j])[ci], wv, acc[j]);
            }
          }
        }
      }
    }
    const float a4c = a4[c];
    #pragma unroll
    for (int j = 0; j < 5; ++j) {
      int pos = p + 2 * j;
      if (pos < 9) {
        int hh = pos / 3, ww = pos - hh * 3;
        vec[c * 9 + ww * 3 + hh] = prelu(acc[j], a4c);
      }
    }
  }
  __syncthreads();

  // ---------- Stage E: dense5 (1152->256) with bf16 weight rows ----------
  {
    const float* vec = smem + VECF;
    float* d5 = smem + D5F;
    const int jj = t;
    const __hip_bfloat16* wrow = w5t + jj * 1152;
    float acc0 = 0.f, acc1 = 0.f, acc2 = 0.f, acc3 = 0.f;
    for (int k = 0; k < 1152; k += 8) {
      uint4 wv = *(const uint4*)(wrow + k);
      float4 x0 = *(const float4*)(vec + k);
      float4 x1 = *(const float4*)(vec + k + 4);
      acc0 = fmaf(x0.x, bf_lo(wv.x), acc0);
      acc1 = fmaf(x0.y, bf_hi(wv.x), acc1);
      acc2 = fmaf(x0.z, bf_lo(wv.y), acc2);
      acc3 = fmaf(x0.w, bf_hi(wv.y), acc3);
      acc0 = fmaf(x1.x, bf_lo(wv.z), acc0);
      acc1 = fmaf(x1.y, bf_hi(wv.z), acc1);
      acc2 = fmaf(x1.z, bf_lo(wv.w), acc2);
      acc3 = fmaf(x1.w, bf_hi(wv.w), acc3);
    }
    float v = (acc0 + acc1) + (acc2 + acc3) + b5[jj];
    d5[jj] = prelu(v, a5[jj]);
  }
  __syncthreads();

  // ---------- Heads ----------
  {
    const float* d5 = smem + D5F;
    float* zz = smem + ZZF;
    const int o = t >> 4, s = t & 15;
    float pa = 0.f;
    if (o < 2) {
      for (int k = s; k < 256; k += 16) pa += d5[k] * wcls[k * 2 + o];
    } else if (o < 6) {
      int oc = o - 2;
      for (int k = s; k < 256; k += 16) pa += d5[k] * wbox[k * 4 + oc];
    } else {
      int oc = o - 6;
      for (int k = s; k < 256; k += 16) pa += d5[k] * wpts[k * 10 + oc];
    }
    pa += __shfl_xor(pa, 1);
    pa += __shfl_xor(pa, 2);
    pa += __shfl_xor(pa, 4);
    pa += __shfl_xor(pa, 8);
    if (s == 0) {
      float bias = (o < 2) ? bcls[o] : (o < 6) ? bbox[o - 2] : bpts[o - 6];
      zz[o] = pa + bias;
    }
  }
  __syncthreads();
  if (t < 16) {
    const float* zz = smem + ZZF;
    int o = t;
    if (o < 2) {
      float z0 = zz[0], z1 = zz[1];
      float m = fmaxf(z0, z1);
      float e0 = __expf(z0 - m), e1 = __expf(z1 - m);
      out[(size_t)img * 2 + o] = ((o == 0) ? e0 : e1) / (e0 + e1);
    } else if (o < 6) {
      out[(size_t)nimg * 2 + (size_t)img * 4 + (o - 2)] = zz[o];
    } else {
      out[(size_t)nimg * 6 + (size_t)img * 10 + (o - 6)] = zz[o];
    }
  }
}

extern "C" void kernel_launch(void* const* d_in, const int* in_sizes, int n_in,
                              void* d_out, int out_size, void* d_ws, size_t ws_size,
                              hipStream_t stream) {
  (void)n_in; (void)out_size; (void)ws_size;
  const float* gin  = (const float*)d_in[0];
  const float* w1   = (const float*)d_in[1];
  const float* b1   = (const float*)d_in[2];
  const float* a1   = (const float*)d_in[3];
  const float* w2   = (const float*)d_in[4];
  const float* b2   = (const float*)d_in[5];
  const float* a2   = (const float*)d_in[6];
  const float* w3   = (const float*)d_in[7];
  const float* b3   = (const float*)d_in[8];
  const float* a3   = (const float*)d_in[9];
  const float* w4   = (const float*)d_in[10];
  const float* b4   = (const float*)d_in[11];
  const float* a4   = (const float*)d_in[12];
  const float* w5   = (const float*)d_in[13];
  const float* b5   = (const float*)d_in[14];
  const float* a5   = (const float*)d_in[15];
  const float* wcls = (const float*)d_in[16];
  const float* bcls = (const float*)d_in[17];
  const float* wbox = (const float*)d_in[18];
  const float* bbox = (const float*)d_in[19];
  const float* wpts = (const float*)d_in[20];
  const float* bpts = (const float*)d_in[21];
  float* out = (float*)d_out;
  __hip_bfloat16* wst = (__hip_bfloat16*)d_ws;
  const int nimg = in_sizes[0] / 6912;   // 4096

  prep_weights<<<WS_ELEMS / 256, 256, 0, stream>>>(w2, w3, w5, wst);
  onet_kernel<<<nimg, 256, 0, stream>>>(gin, w1, b1, a1, b2, a2, b3, a3,
                                        w4, b4, a4, b5, a5,
                                        wcls, bcls, wbox, bbox, wpts, bpts,
                                        wst, out, nimg);
}

// Round 4
// 816.055 us; speedup vs baseline: 3.5319x; 1.2556x over previous
//
#include <hip/hip_runtime.h>
#include <hip/hip_bf16.h>

typedef __attribute__((ext_vector_type(8))) short short8;   // 8 bf16 (MFMA A/B frag)
typedef __attribute__((ext_vector_type(4))) float f32x4;    // MFMA C/D frag
typedef __attribute__((ext_vector_type(4))) unsigned u32x4;

__device__ __forceinline__ float bf_lo(unsigned v) { return __uint_as_float(v << 16); }
__device__ __forceinline__ float bf_hi(unsigned v) { return __uint_as_float(v & 0xFFFF0000u); }
__device__ __forceinline__ float prelu(float v, float a) { return v >= 0.0f ? v : v * a; }
__device__ __forceinline__ float max3f(float a, float b, float c) { return fmaxf(fmaxf(a, b), c); }

// ---- LDS layout (float offsets) ----
// conv1 phase: pool1 bf16 [529][40] @P1F (10580 fl) + in2 bf16 [48][2copies*160] @IN2F (7680 fl)
// stage B:     cb2 bf16 [3][21][64] @CB2F + pool2 bf16 [100][72] @P2F   (overlay in2)
// stage C/D:   c3 fp32 [64][64] @0, pool3b bf16 [16][72], vec fp32[1152], d5[256], zz[16]
#define P1F   0
#define IN2F  10580
#define CB2F  10580
#define P2F   12596
#define C3F   0
#define P3BF  4096
#define VECF  4672
#define D5F   5824
#define ZZF   6080
#define SMF   18260      // 73,040 B -> 2 blocks/CU
#define IN2B  (IN2F * 4)

// ---- d_ws layout (bf16 elems) ----
// w1t[co(32)][k(32: kh*9+3kw+ci, pad>=27)] | w2t[9][64co][32k] | w3t[9][2cg][64co][32k]
// w4t[co(128)][k(256: khkw*64+ci)] | w5t[256jj][1152k]
#define W1T 0
#define W2T 1536
#define W3T 19968
#define W4T 56832
#define W5T 89600
#define WS_ELEMS 384512

__global__ void prep_weights(const float* __restrict__ w1, const float* __restrict__ w2,
                             const float* __restrict__ w3, const float* __restrict__ w4,
                             const float* __restrict__ w5, __hip_bfloat16* __restrict__ ws) {
  int i = blockIdx.x * 256 + threadIdx.x;
  if (i >= WS_ELEMS) return;
  float v = 0.f;
  if (i < W2T) {
    int co = i >> 5, k = i & 31;
    if (k < 27) { int kh = k / 9, r = k % 9, kw = r / 3, ci = r % 3; v = w1[((kh * 3 + kw) * 3 + ci) * 32 + co]; }
  } else if (i < W3T) {
    int j = i - W2T; int khkw = j >> 11, rem = j & 2047, co = rem >> 5, k = rem & 31;
    v = w2[(khkw * 32 + k) * 64 + co];
  } else if (i < W4T) {
    int j = i - W3T; int khkwcg = j >> 11, rem = j & 2047, co = rem >> 5, k = rem & 31;
    v = w3[((khkwcg >> 1) * 64 + (khkwcg & 1) * 32 + k) * 64 + co];
  } else if (i < W5T) {
    int j = i - W4T; int co = j >> 8, k = j & 255; int khkw = k >> 6, ci = k & 63;
    v = w4[(khkw * 64 + ci) * 128 + co];
  } else {
    int j = i - W5T; int jj = j / 1152, k = j - jj * 1152;
    v = w5[k * 256 + jj];
  }
  ws[i] = __float2bfloat16(v);
}

__global__ __launch_bounds__(256, 2)
void onet_kernel(const float* __restrict__ gin,
                 const float* __restrict__ b1, const float* __restrict__ a1,
                 const float* __restrict__ b2, const float* __restrict__ a2,
                 const float* __restrict__ b3, const float* __restrict__ a3,
                 const float* __restrict__ b4, const float* __restrict__ a4,
                 const float* __restrict__ b5, const float* __restrict__ a5,
                 const float* __restrict__ wcls, const float* __restrict__ bcls,
                 const float* __restrict__ wbox, const float* __restrict__ bbox,
                 const float* __restrict__ wpts, const float* __restrict__ bpts,
                 const __hip_bfloat16* __restrict__ ws,
                 float* __restrict__ out, int nimg)
{
  __shared__ __align__(16) float smem[SMF];
  const int t = threadIdx.x;
  const int img = blockIdx.x;
  const int lane = t & 63, wid = t >> 6;
  const int lr = lane & 15, lg = lane >> 4;
  const bool isLg3 = (lg == 3);
  const __hip_bfloat16* w1t = ws + W1T;
  const __hip_bfloat16* w2t = ws + W2T;
  const __hip_bfloat16* w3t = ws + W3T;
  const __hip_bfloat16* w4t = ws + W4T;
  const __hip_bfloat16* w5t = ws + W5T;

  // ---------- Stage A: input -> LDS, 2 element-shifted bf16 copies per row ----------
  // row block = 640B: copy0 elems [0..159] (144 real + zero pad); copy1[s] = elem s+1
  {
    char* sb = (char*)smem + IN2B;
    // zero the pads: per row: c0 bytes [288,320) 8 dwords; c1 u16@606 + dwords [608,640)
    for (int u = t; u < 48 * 17; u += 256) {
      int row = u / 17, q = u - row * 17;
      char* rp = sb + row * 640;
      if (q < 8)       *(unsigned*)(rp + 288 + 4 * q) = 0u;
      else if (q < 16) *(unsigned*)(rp + 608 + 4 * (q - 8)) = 0u;
      else             *(unsigned short*)(rp + 606) = 0;
    }
    const float* inp = gin + (size_t)img * 6912;
    for (int i = t; i < 6912; i += 256) {
      int h = i / 144, e = i - h * 144;
      unsigned short b = __bfloat16_as_ushort(__float2bfloat16(inp[i]));
      char* rp = sb + h * 640;
      *(unsigned short*)(rp + e * 2) = b;
      if (e) *(unsigned short*)(rp + 320 + (e - 1) * 2) = b;
    }
  }
  __syncthreads();

  // ---------- conv1 (3x3x3->32) via MFMA 16x16x32 + PReLU + pool1 in registers ----------
  // K = kh*9 + 3*kw + ci (27 real, pad 32). A-frag built from 5 aligned ds_read_b32 via
  // the shifted-copy trick. C layout: col=lane&15=ch, row=4*lg+reg=position.
  {
    short8 bf1c[2];
    float bias1[2], al1[2];
    #pragma unroll
    for (int n = 0; n < 2; ++n) {
      bf1c[n] = *(const short8*)(w1t + (n * 16 + lr) * 32 + 8 * lg);
      bias1[n] = b1[n * 16 + lr];
      al1[n] = a1[n * 16 + lr];
    }
    const unsigned selc = (lg == 1) ? 0x05040100u : 0x03020100u;
    const unsigned m1c = (lg == 3) ? 0x0000FFFFu : ~0u;
    const unsigned mzc = (lg == 3) ? 0u : ~0u;
    int offv[3][5];
    #pragma unroll
    for (int wt = 0; wt < 3; ++wt) {
      int w = 16 * wt + lr;
      int X[5], KH[5];
      if (lg == 0)      { X[0]=3*w;   X[1]=3*w+2; X[2]=3*w+4; X[3]=3*w+6; X[4]=3*w; KH[0]=0;KH[1]=0;KH[2]=0;KH[3]=0;KH[4]=0; }
      else if (lg == 1) { X[0]=3*w+8; X[1]=3*w+1; X[2]=3*w+3; X[3]=3*w+5; X[4]=3*w; KH[0]=0;KH[1]=1;KH[2]=1;KH[3]=1;KH[4]=1; }
      else if (lg == 2) { X[0]=3*w+7; X[1]=3*w;   X[2]=3*w+2; X[3]=3*w+4; X[4]=3*w; KH[0]=1;KH[1]=2;KH[2]=2;KH[3]=2;KH[4]=2; }
      else              { X[0]=3*w+6; X[1]=3*w+8; X[2]=3*w;   X[3]=3*w;   X[4]=3*w; KH[0]=2;KH[1]=2;KH[2]=2;KH[3]=2;KH[4]=2; }
      #pragma unroll
      for (int i = 0; i < 5; ++i)
        offv[wt][i] = KH[i] * 640 + 2 * X[i] + ((X[i] & 1) ? 318 : 0);
    }

    auto compute_row = [&](int h, float (&cur)[3][2][2]) {
      if (h > 45) {
        #pragma unroll
        for (int wt = 0; wt < 3; ++wt)
          #pragma unroll
          for (int n = 0; n < 2; ++n) { cur[wt][n][0] = -1e30f; cur[wt][n][1] = -1e30f; }
        return;
      }
      const char* rowp = (const char*)smem + IN2B + h * 640;
      float v[3][2][4];
      #pragma unroll
      for (int wt = 0; wt < 3; ++wt) {
        unsigned r0 = *(const unsigned*)(rowp + offv[wt][0]);
        unsigned r1 = *(const unsigned*)(rowp + offv[wt][1]);
        unsigned r2 = *(const unsigned*)(rowp + offv[wt][2]);
        unsigned r3 = *(const unsigned*)(rowp + offv[wt][3]);
        unsigned r4 = *(const unsigned*)(rowp + offv[wt][4]);
        u32x4 iv = (u32x4){__builtin_amdgcn_perm(r4, r0, selc), r1 & m1c, r2 & mzc, r3 & mzc};
        short8 af = __builtin_bit_cast(short8, iv);
        #pragma unroll
        for (int n = 0; n < 2; ++n) {
          f32x4 acc = (f32x4){bias1[n], bias1[n], bias1[n], bias1[n]};
          acc = __builtin_amdgcn_mfma_f32_16x16x32_bf16(af, bf1c[n], acc, 0, 0, 0);
          #pragma unroll
          for (int reg = 0; reg < 4; ++reg) v[wt][n][reg] = prelu(acc[reg], al1[n]);
        }
      }
      if (isLg3) {   // positions w=46,47 in tile 2 are garbage
        #pragma unroll
        for (int n = 0; n < 2; ++n) { v[2][n][2] = -1e30f; v[2][n][3] = -1e30f; }
      }
      #pragma unroll
      for (int n = 0; n < 2; ++n) {
        float hd0 = __shfl_down(v[0][n][0], 16);
        float hd1 = __shfl_down(v[1][n][0], 16);
        float hd2 = __shfl_down(v[2][n][0], 16);
        float hx1 = __shfl(v[1][n][0], lr);   // tile1 w=16 head (for lg3 of tile0)
        float hx2 = __shfl(v[2][n][0], lr);   // tile2 w=32 head (for lg3 of tile1)
        float h0 = isLg3 ? hx1 : hd0;
        float h1 = isLg3 ? hx2 : hd1;
        cur[0][n][0] = max3f(v[0][n][0], v[0][n][1], v[0][n][2]);
        cur[0][n][1] = max3f(v[0][n][2], v[0][n][3], h0);
        cur[1][n][0] = max3f(v[1][n][0], v[1][n][1], v[1][n][2]);
        cur[1][n][1] = max3f(v[1][n][2], v[1][n][3], h1);
        cur[2][n][0] = max3f(v[2][n][0], v[2][n][1], v[2][n][2]);
        cur[2][n][1] = max3f(v[2][n][2], v[2][n][3], hd2);   // lg3: pw=23, dropped at store
      }
    };

    __hip_bfloat16* pool1 = (__hip_bfloat16*)(smem + P1F);
    auto emit = [&](int r, float (&pa)[3][2][2], float (&pb)[3][2][2], float (&pc)[3][2][2]) {
      #pragma unroll
      for (int wt = 0; wt < 3; ++wt)
        #pragma unroll
        for (int n = 0; n < 2; ++n)
          #pragma unroll
          for (int pp = 0; pp < 2; ++pp) {
            float m = max3f(pa[wt][n][pp], pb[wt][n][pp], pc[wt][n][pp]);
            int pw = 8 * wt + 2 * lg + pp;
            if (pw < 23)
              pool1[(r * 23 + pw) * 40 + n * 16 + lr] = __float2bfloat16(m);
          }
    };

    const int pr0 = wid * 6;
    const int pr1 = (pr0 + 5 < 23) ? pr0 + 5 : 22;
    float pa[3][2][2], pb[3][2][2], pc[3][2][2];
    compute_row(2 * pr0, pa);
    compute_row(2 * pr0 + 1, pb);
    for (int r = pr0; r <= pr1; ++r) {
      compute_row(2 * r + 2, pc);
      emit(r, pa, pb, pc);
      if (r < pr1) {
        #pragma unroll
        for (int wt = 0; wt < 3; ++wt)
          #pragma unroll
          for (int n = 0; n < 2; ++n) { pa[wt][n][0] = pc[wt][n][0]; pa[wt][n][1] = pc[wt][n][1]; }
        compute_row(2 * r + 3, pb);
      }
    }
  }
  __syncthreads();

  // ---------- Stage B: conv2 (3x3x32->64) via MFMA + pool2 ----------
  {
    const __hip_bfloat16* pool1b = (const __hip_bfloat16*)(smem + P1F);
    __hip_bfloat16* cb2 = (__hip_bfloat16*)(smem + CB2F);    // [3][21][64]
    __hip_bfloat16* pool2 = (__hip_bfloat16*)(smem + P2F);   // [100][72]
    const int wv = wid;
    short8 bfr[9][4];
    #pragma unroll
    for (int khkw = 0; khkw < 9; ++khkw)
      #pragma unroll
      for (int nt = 0; nt < 4; ++nt)
        bfr[khkw][nt] = *(const short8*)(w2t + ((khkw * 64 + nt * 16 + lr) * 32 + 8 * lg));
    int mA = wv * 16 + lr; if (mA > 62) mA = 62;
    const int krA = mA / 21, owA = mA - krA * 21;
    int mc[4], krc[4], owc[4];
    #pragma unroll
    for (int reg = 0; reg < 4; ++reg) {
      mc[reg] = wv * 16 + lg * 4 + reg;
      krc[reg] = mc[reg] / 21;
      owc[reg] = mc[reg] - krc[reg] * 21;
    }
    float bsn[4], alv[4];
    #pragma unroll
    for (int nt = 0; nt < 4; ++nt) { bsn[nt] = b2[nt * 16 + lr]; alv[nt] = a2[nt * 16 + lr]; }

    for (int r = 0; r < 10; ++r) {
      const int posA = (2 * r + krA) * 23 + owA;
      f32x4 acc[4];
      #pragma unroll
      for (int nt = 0; nt < 4; ++nt) acc[nt] = (f32x4){bsn[nt], bsn[nt], bsn[nt], bsn[nt]};
      #pragma unroll
      for (int kh = 0; kh < 3; ++kh)
        #pragma unroll
        for (int kw = 0; kw < 3; ++kw) {
          short8 af = *(const short8*)(pool1b + (posA + kh * 23 + kw) * 40 + 8 * lg);
          #pragma unroll
          for (int nt = 0; nt < 4; ++nt)
            acc[nt] = __builtin_amdgcn_mfma_f32_16x16x32_bf16(af, bfr[kh * 3 + kw][nt], acc[nt], 0, 0, 0);
        }
      #pragma unroll
      for (int nt = 0; nt < 4; ++nt)
        #pragma unroll
        for (int reg = 0; reg < 4; ++reg)
          if (mc[reg] < 63)
            cb2[(krc[reg] * 21 + owc[reg]) * 64 + nt * 16 + lr] =
                __float2bfloat16(prelu(acc[nt][reg], alv[nt]));
      __syncthreads();
      {
        const int ch = t & 63;
        #pragma unroll
        for (int jj = 0; jj < 3; ++jj) {
          int w = (t >> 6) + 4 * jj;
          if (w < 10) {
            float m = -1e30f;
            #pragma unroll
            for (int kh = 0; kh < 3; ++kh)
              #pragma unroll
              for (int kw = 0; kw < 3; ++kw)
                m = fmaxf(m, __bfloat162float(cb2[(kh * 21 + 2 * w + kw) * 64 + ch]));
            pool2[(r * 10 + w) * 72 + ch] = __float2bfloat16(m);
          }
        }
      }
      __syncthreads();
    }
  }

  // ---------- Stage C: conv3 (3x3x64->64) via MFMA -> c3 fp32 [64][64] ----------
  {
    const __hip_bfloat16* pool2b = (const __hip_bfloat16*)(smem + P2F);
    float* c3 = smem + C3F;
    const int nt = wid;
    short8 bfr[9][2];
    #pragma unroll
    for (int khkw = 0; khkw < 9; ++khkw)
      #pragma unroll
      for (int cg = 0; cg < 2; ++cg)
        bfr[khkw][cg] = *(const short8*)(w3t + (((khkw * 2 + cg) * 64 + nt * 16 + lr) * 32 + 8 * lg));
    const float bs = b3[nt * 16 + lr], al = a3[nt * 16 + lr];
    #pragma unroll
    for (int mt = 0; mt < 4; ++mt) {
      const int mA = mt * 16 + lr;
      const int ohA = mA >> 3, owA = mA & 7;
      f32x4 acc = (f32x4){bs, bs, bs, bs};
      #pragma unroll
      for (int kh = 0; kh < 3; ++kh)
        #pragma unroll
        for (int kw = 0; kw < 3; ++kw)
          #pragma unroll
          for (int cg = 0; cg < 2; ++cg) {
            short8 af = *(const short8*)(pool2b + ((ohA + kh) * 10 + owA + kw) * 72 + cg * 32 + 8 * lg);
            acc = __builtin_amdgcn_mfma_f32_16x16x32_bf16(af, bfr[kh * 3 + kw][cg], acc, 0, 0, 0);
          }
      #pragma unroll
      for (int reg = 0; reg < 4; ++reg) {
        int m = mt * 16 + lg * 4 + reg;
        c3[m * 64 + nt * 16 + lr] = prelu(acc[reg], al);
      }
    }
  }
  __syncthreads();

  // ---------- pool3 (2x2 s2) -> bf16 [16][72] ----------
  {
    const float* c3 = smem + C3F;
    __hip_bfloat16* pool3b = (__hip_bfloat16*)(smem + P3BF);
    const int c = t & 31;
    const int p = t >> 5;
    #pragma unroll
    for (int j = 0; j < 2; ++j) {
      int pos = p + 8 * j;
      int pi = pos >> 2, pj = pos & 3;
      #pragma unroll
      for (int e = 0; e < 2; ++e) {
        int ch = c + 32 * e;
        float m = fmaxf(
            fmaxf(c3[((2 * pi) * 8 + 2 * pj) * 64 + ch],     c3[((2 * pi) * 8 + 2 * pj + 1) * 64 + ch]),
            fmaxf(c3[((2 * pi + 1) * 8 + 2 * pj) * 64 + ch], c3[((2 * pi + 1) * 8 + 2 * pj + 1) * 64 + ch]));
        pool3b[(pi * 4 + pj) * 72 + ch] = __float2bfloat16(m);
      }
    }
  }
  __syncthreads();

  // ---------- conv4 (2x2x64->128) via MFMA -> vec[c*9 + w*3 + h] ----------
  {
    const __hip_bfloat16* pool3b = (const __hip_bfloat16*)(smem + P3BF);
    float* vec = smem + VECF;
    int pos = lr < 9 ? lr : 8;
    int hh = pos / 3, wwp = pos - hh * 3;
    short8 afr[8];
    #pragma unroll
    for (int s = 0; s < 8; ++s) {
      int khkw = s >> 1, kh = khkw >> 1, kw = khkw & 1;
      int cb = (s & 1) * 32 + 8 * lg;
      afr[s] = *(const short8*)(pool3b + ((hh + kh) * 4 + (wwp + kw)) * 72 + cb);
    }
    #pragma unroll
    for (int q = 0; q < 2; ++q) {
      int co = (wid * 2 + q) * 16 + lr;
      float bb = b4[co];
      f32x4 acc = (f32x4){bb, bb, bb, bb};
      #pragma unroll
      for (int s = 0; s < 8; ++s) {
        short8 bfr = *(const short8*)(w4t + co * 256 + s * 32 + 8 * lg);
        acc = __builtin_amdgcn_mfma_f32_16x16x32_bf16(afr[s], bfr, acc, 0, 0, 0);
      }
      float al = a4[co];
      #pragma unroll
      for (int reg = 0; reg < 4; ++reg) {
        int pp = 4 * lg + reg;
        if (pp < 9) {
          int h9 = pp / 3, w9 = pp - h9 * 3;
          vec[co * 9 + w9 * 3 + h9] = prelu(acc[reg], al);
        }
      }
    }
  }
  __syncthreads();

  // ---------- dense5 (1152->256) + PReLU ----------
  {
    const float* vec = smem + VECF;
    float* d5 = smem + D5F;
    const int jj = t;
    const __hip_bfloat16* wrow = w5t + jj * 1152;
    float acc0 = 0.f, acc1 = 0.f, acc2 = 0.f, acc3 = 0.f;
    for (int k = 0; k < 1152; k += 8) {
      uint4 wv = *(const uint4*)(wrow + k);
      float4 x0 = *(const float4*)(vec + k);
      float4 x1 = *(const float4*)(vec + k + 4);
      acc0 = fmaf(x0.x, bf_lo(wv.x), acc0);
      acc1 = fmaf(x0.y, bf_hi(wv.x), acc1);
      acc2 = fmaf(x0.z, bf_lo(wv.y), acc2);
      acc3 = fmaf(x0.w, bf_hi(wv.y), acc3);
      acc0 = fmaf(x1.x, bf_lo(wv.z), acc0);
      acc1 = fmaf(x1.y, bf_hi(wv.z), acc1);
      acc2 = fmaf(x1.z, bf_lo(wv.w), acc2);
      acc3 = fmaf(x1.w, bf_hi(wv.w), acc3);
    }
    float v = (acc0 + acc1) + (acc2 + acc3) + b5[jj];
    d5[jj] = prelu(v, a5[jj]);
  }
  __syncthreads();

  // ---------- Heads ----------
  {
    const float* d5 = smem + D5F;
    float* zz = smem + ZZF;
    const int o = t >> 4, s = t & 15;
    float pa = 0.f;
    if (o < 2) {
      for (int k = s; k < 256; k += 16) pa += d5[k] * wcls[k * 2 + o];
    } else if (o < 6) {
      int oc = o - 2;
      for (int k = s; k < 256; k += 16) pa += d5[k] * wbox[k * 4 + oc];
    } else {
      int oc = o - 6;
      for (int k = s; k < 256; k += 16) pa += d5[k] * wpts[k * 10 + oc];
    }
    pa += __shfl_xor(pa, 1);
    pa += __shfl_xor(pa, 2);
    pa += __shfl_xor(pa, 4);
    pa += __shfl_xor(pa, 8);
    if (s == 0) {
      float bias = (o < 2) ? bcls[o] : (o < 6) ? bbox[o - 2] : bpts[o - 6];
      zz[o] = pa + bias;
    }
  }
  __syncthreads();
  if (t < 16) {
    const float* zz = smem + ZZF;
    int o = t;
    if (o < 2) {
      float z0 = zz[0], z1 = zz[1];
      float m = fmaxf(z0, z1);
      float e0 = __expf(z0 - m), e1 = __expf(z1 - m);
      out[(size_t)img * 2 + o] = ((o == 0) ? e0 : e1) / (e0 + e1);
    } else if (o < 6) {
      out[(size_t)nimg * 2 + (size_t)img * 4 + (o - 2)] = zz[o];
    } else {
      out[(size_t)nimg * 6 + (size_t)img * 10 + (o - 6)] = zz[o];
    }
  }
}

extern "C" void kernel_launch(void* const* d_in, const int* in_sizes, int n_in,
                              void* d_out, int out_size, void* d_ws, size_t ws_size,
                              hipStream_t stream) {
  (void)n_in; (void)out_size; (void)ws_size;
  const float* gin  = (const float*)d_in[0];
  const float* w1   = (const float*)d_in[1];
  const float* b1   = (const float*)d_in[2];
  const float* a1   = (const float*)d_in[3];
  const float* w2   = (const float*)d_in[4];
  const float* b2   = (const float*)d_in[5];
  const float* a2   = (const float*)d_in[6];
  const float* w3   = (const float*)d_in[7];
  const float* b3   = (const float*)d_in[8];
  const float* a3   = (const float*)d_in[9];
  const float* w4   = (const float*)d_in[10];
  const float* b4   = (const float*)d_in[11];
  const float* a4   = (const float*)d_in[12];
  const float* w5   = (const float*)d_in[13];
  const float* b5   = (const float*)d_in[14];
  const float* a5   = (const float*)d_in[15];
  const float* wcls = (const float*)d_in[16];
  const float* bcls = (const float*)d_in[17];
  const float* wbox = (const float*)d_in[18];
  const float* bbox = (const float*)d_in[19];
  const float* wpts = (const float*)d_in[20];
  const float* bpts = (const float*)d_in[21];
  float* out = (float*)d_out;
  __hip_bfloat16* wst = (__hip_bfloat16*)d_ws;
  const int nimg = in_sizes[0] / 6912;   // 4096

  prep_weights<<<(WS_ELEMS + 255) / 256, 256, 0, stream>>>(w1, w2, w3, w4, w5, wst);
  onet_kernel<<<nimg, 256, 0, stream>>>(gin, b1, a1, b2, a2, b3, a3,
                                        b4, a4, b5, a5,
                                        wcls, bcls, wbox, bbox, wpts, bpts,
                                        wst, out, nimg);
}

// Round 5
// 750.428 us; speedup vs baseline: 3.8408x; 1.0875x over previous
//
#include <hip/hip_runtime.h>
#include <hip/hip_bf16.h>

typedef __attribute__((ext_vector_type(8))) short short8;   // 8 bf16 (MFMA A/B frag)
typedef __attribute__((ext_vector_type(4))) float f32x4;    // MFMA C/D frag
typedef __attribute__((ext_vector_type(4))) unsigned u32x4;

__device__ __forceinline__ float bf_lo(unsigned v) { return __uint_as_float(v << 16); }
__device__ __forceinline__ float bf_hi(unsigned v) { return __uint_as_float(v & 0xFFFF0000u); }
__device__ __forceinline__ float prelu(float v, float a) { return v >= 0.0f ? v : v * a; }
__device__ __forceinline__ float max3f(float a, float b, float c) { return fmaxf(fmaxf(a, b), c); }

// ---- main-kernel LDS (bytes) ----
// [0, 42320)      pool1 bf16 [529 pos][40 ch]  (pool2 embedded later: row r at byte r*3680, [10 w][72 ch])
// [42320, 53584)  region X: conv1: in2 19 rows x 592 B  |  stage B: cb2 bf16 [3][21][64] (8064 B)
//                 | tail: pool3b bf16 [16][72] (2304 B)
#define XB   42320
#define SMB  53584          // 3 blocks/CU even at 512-B LDS granularity

// ---- d_ws layout (bf16 elems) ----
#define W1T 0
#define W2T 1536
#define W3T 19968
#define W4T 56832
#define W5T 89600
#define WS_ELEMS 384512

__device__ __hip_bfloat16 vec_g[4096ull * 1152];   // conv4 output (flattened permuted vec)

__global__ void prep_weights(const float* __restrict__ w1, const float* __restrict__ w2,
                             const float* __restrict__ w3, const float* __restrict__ w4,
                             const float* __restrict__ w5, __hip_bfloat16* __restrict__ ws) {
  int i = blockIdx.x * 256 + threadIdx.x;
  if (i >= WS_ELEMS) return;
  float v = 0.f;
  if (i < W2T) {
    int co = i >> 5, k = i & 31;
    if (k < 27) { int kh = k / 9, r = k % 9, kw = r / 3, ci = r % 3; v = w1[((kh * 3 + kw) * 3 + ci) * 32 + co]; }
  } else if (i < W3T) {
    int j = i - W2T; int khkw = j >> 11, rem = j & 2047, co = rem >> 5, k = rem & 31;
    v = w2[(khkw * 32 + k) * 64 + co];
  } else if (i < W4T) {
    int j = i - W3T; int khkwcg = j >> 11, rem = j & 2047, co = rem >> 5, k = rem & 31;
    v = w3[((khkwcg >> 1) * 64 + (khkwcg & 1) * 32 + k) * 64 + co];
  } else if (i < W5T) {
    int j = i - W4T; int co = j >> 8, k = j & 255; int khkw = k >> 6, ci = k & 63;
    v = w4[(khkw * 64 + ci) * 128 + co];
  } else {
    int j = i - W5T; int jj = j / 1152, k = j - jj * 1152;
    v = w5[k * 256 + jj];
  }
  ws[i] = __float2bfloat16(v);
}

__global__ __launch_bounds__(256, 3)
void onet_kernel(const float* __restrict__ gin,
                 const float* __restrict__ b1, const float* __restrict__ a1,
                 const float* __restrict__ b2, const float* __restrict__ a2,
                 const float* __restrict__ b3, const float* __restrict__ a3,
                 const float* __restrict__ b4, const float* __restrict__ a4,
                 const __hip_bfloat16* __restrict__ ws, int nimg)
{
  __shared__ __align__(16) char smemc[SMB];
  const int t = threadIdx.x;
  const int img = blockIdx.x;
  const int lane = t & 63, wid = t >> 6;
  const int lr = lane & 15, lg = lane >> 4;
  const bool isLg3 = (lg == 3);
  const __hip_bfloat16* w1t = ws + W1T;
  const __hip_bfloat16* w2t = ws + W2T;
  const __hip_bfloat16* w3t = ws + W3T;
  const __hip_bfloat16* w4t = ws + W4T;

  // ================= conv1 (3x3x3->32) MFMA + pool1, 3 input phases =================
  // in2 row block (592 B): copy0 elems 0..143 @ [0,288) pad [288,296);
  //                        copy1 slot s = elem s+1 @ 296+2s, s=0..142, pad [582,592)
  {
    __hip_bfloat16* pool1 = (__hip_bfloat16*)smemc;
    char* in2 = smemc + XB;
    short8 bf1c[2];
    float bias1[2], al1[2];
    #pragma unroll
    for (int n = 0; n < 2; ++n) {
      bf1c[n] = *(const short8*)(w1t + (n * 16 + lr) * 32 + 8 * lg);
      bias1[n] = b1[n * 16 + lr];
      al1[n] = a1[n * 16 + lr];
    }
    const unsigned selc = (lg == 1) ? 0x05040100u : 0x03020100u;
    const unsigned m1c = (lg == 3) ? 0x0000FFFFu : ~0u;
    const unsigned mzc = (lg == 3) ? 0u : ~0u;
    int offv[3][5];
    #pragma unroll
    for (int wt = 0; wt < 3; ++wt) {
      int w = 16 * wt + lr;
      int X[5], KH[5];
      if (lg == 0)      { X[0]=3*w;   X[1]=3*w+2; X[2]=3*w+4; X[3]=3*w+6; X[4]=3*w; KH[0]=0;KH[1]=0;KH[2]=0;KH[3]=0;KH[4]=0; }
      else if (lg == 1) { X[0]=3*w+8; X[1]=3*w+1; X[2]=3*w+3; X[3]=3*w+5; X[4]=3*w; KH[0]=0;KH[1]=1;KH[2]=1;KH[3]=1;KH[4]=1; }
      else if (lg == 2) { X[0]=3*w+7; X[1]=3*w;   X[2]=3*w+2; X[3]=3*w+4; X[4]=3*w; KH[0]=1;KH[1]=2;KH[2]=2;KH[3]=2;KH[4]=2; }
      else              { X[0]=3*w+6; X[1]=3*w+8; X[2]=3*w;   X[3]=3*w;   X[4]=3*w; KH[0]=2;KH[1]=2;KH[2]=2;KH[3]=2;KH[4]=2; }
      #pragma unroll
      for (int i = 0; i < 5; ++i)
        offv[wt][i] = KH[i] * 592 + 2 * X[i] + ((X[i] & 1) ? 294 : 0);
    }

    auto compute_row = [&](int h, int base, float (&cur)[3][2][2]) {
      if (h > 45) {
        #pragma unroll
        for (int wt = 0; wt < 3; ++wt)
          #pragma unroll
          for (int n = 0; n < 2; ++n) { cur[wt][n][0] = -1e30f; cur[wt][n][1] = -1e30f; }
        return;
      }
      const char* rowp = in2 + (h - base) * 592;
      float v[3][2][4];
      #pragma unroll
      for (int wt = 0; wt < 3; ++wt) {
        unsigned r0 = *(const unsigned*)(rowp + offv[wt][0]);
        unsigned r1 = *(const unsigned*)(rowp + offv[wt][1]);
        unsigned r2 = *(const unsigned*)(rowp + offv[wt][2]);
        unsigned r3 = *(const unsigned*)(rowp + offv[wt][3]);
        unsigned r4 = *(const unsigned*)(rowp + offv[wt][4]);
        u32x4 iv = (u32x4){__builtin_amdgcn_perm(r4, r0, selc), r1 & m1c, r2 & mzc, r3 & mzc};
        short8 af = __builtin_bit_cast(short8, iv);
        #pragma unroll
        for (int n = 0; n < 2; ++n) {
          f32x4 acc = (f32x4){bias1[n], bias1[n], bias1[n], bias1[n]};
          acc = __builtin_amdgcn_mfma_f32_16x16x32_bf16(af, bf1c[n], acc, 0, 0, 0);
          #pragma unroll
          for (int reg = 0; reg < 4; ++reg) v[wt][n][reg] = prelu(acc[reg], al1[n]);
        }
      }
      if (isLg3) {
        #pragma unroll
        for (int n = 0; n < 2; ++n) { v[2][n][2] = -1e30f; v[2][n][3] = -1e30f; }
      }
      #pragma unroll
      for (int n = 0; n < 2; ++n) {
        float hd0 = __shfl_down(v[0][n][0], 16);
        float hd1 = __shfl_down(v[1][n][0], 16);
        float hd2 = __shfl_down(v[2][n][0], 16);
        float hx1 = __shfl(v[1][n][0], lr);
        float hx2 = __shfl(v[2][n][0], lr);
        float h0 = isLg3 ? hx1 : hd0;
        float h1 = isLg3 ? hx2 : hd1;
        cur[0][n][0] = max3f(v[0][n][0], v[0][n][1], v[0][n][2]);
        cur[0][n][1] = max3f(v[0][n][2], v[0][n][3], h0);
        cur[1][n][0] = max3f(v[1][n][0], v[1][n][1], v[1][n][2]);
        cur[1][n][1] = max3f(v[1][n][2], v[1][n][3], h1);
        cur[2][n][0] = max3f(v[2][n][0], v[2][n][1], v[2][n][2]);
        cur[2][n][1] = max3f(v[2][n][2], v[2][n][3], hd2);
      }
    };

    auto emit = [&](int r, float (&pa)[3][2][2], float (&pb)[3][2][2], float (&pc)[3][2][2]) {
      #pragma unroll
      for (int wt = 0; wt < 3; ++wt)
        #pragma unroll
        for (int n = 0; n < 2; ++n)
          #pragma unroll
          for (int pp = 0; pp < 2; ++pp) {
            float m = max3f(pa[wt][n][pp], pb[wt][n][pp], pc[wt][n][pp]);
            int pw = 8 * wt + 2 * lg + pp;
            if (pw < 23)
              pool1[(r * 23 + pw) * 40 + n * 16 + lr] = __float2bfloat16(m);
          }
    };

    // zero in2 pads (19 row slots, 5 items each) — pads never touched by data stores
    for (int u = t; u < 95; u += 256) {
      int row = u / 5, q = u - row * 5;
      char* rp = in2 + row * 592;
      if (q < 2)      *(unsigned*)(rp + 288 + 4 * q) = 0u;
      else if (q < 4) *(unsigned*)(rp + 584 + 4 * (q - 2)) = 0u;
      else            *(unsigned short*)(rp + 582) = 0;
    }

    const int base_[3]  = {0, 14, 30};
    const int nrows_[3] = {17, 19, 18};
    const int lo_[3]    = {0, 7, 15};
    const int hi_[3]    = {6, 14, 22};
    for (int ph = 0; ph < 3; ++ph) {
      if (ph) __syncthreads();             // previous phase done reading in2
      const int base = base_[ph];
      {
        const float* inp = gin + (size_t)img * 6912 + base * 144;
        const int ne = nrows_[ph] * 144;
        for (int i = t; i < ne; i += 256) {
          int rl = i / 144, e = i - rl * 144;
          unsigned short b = __bfloat16_as_ushort(__float2bfloat16(inp[i]));
          char* rp = in2 + rl * 592;
          *(unsigned short*)(rp + 2 * e) = b;
          if (e) *(unsigned short*)(rp + 2 * e + 294) = b;
        }
      }
      __syncthreads();
      int r0 = lo_[ph] + 2 * wid;
      if (r0 <= hi_[ph]) {
        int r1 = (r0 + 1 <= hi_[ph]) ? r0 + 1 : r0;
        float pa[3][2][2], pb[3][2][2], pc[3][2][2];
        compute_row(2 * r0,     base, pa);
        compute_row(2 * r0 + 1, base, pb);
        compute_row(2 * r0 + 2, base, pc);
        emit(r0, pa, pb, pc);
        if (r1 > r0) {
          #pragma unroll
          for (int wt = 0; wt < 3; ++wt)
            #pragma unroll
            for (int n = 0; n < 2; ++n) { pa[wt][n][0] = pc[wt][n][0]; pa[wt][n][1] = pc[wt][n][1]; }
          compute_row(2 * r0 + 3, base, pb);
          compute_row(2 * r0 + 4, base, pc);
          emit(r1, pa, pb, pc);
        }
      }
    }
  }
  __syncthreads();

  // ================= stage B: conv2 (3x3x32->64) MFMA + pool2 (embedded in pool1) =================
  {
    const __hip_bfloat16* pool1b = (const __hip_bfloat16*)smemc;
    __hip_bfloat16* cb2 = (__hip_bfloat16*)(smemc + XB);     // [3][21][64]
    const int wv = wid;
    short8 bfr[9][4];
    #pragma unroll
    for (int khkw = 0; khkw < 9; ++khkw)
      #pragma unroll
      for (int nt = 0; nt < 4; ++nt)
        bfr[khkw][nt] = *(const short8*)(w2t + ((khkw * 64 + nt * 16 + lr) * 32 + 8 * lg));
    int mA = wv * 16 + lr; if (mA > 62) mA = 62;
    const int krA = mA / 21, owA = mA - krA * 21;
    int mc[4], krc[4], owc[4];
    #pragma unroll
    for (int reg = 0; reg < 4; ++reg) {
      mc[reg] = wv * 16 + lg * 4 + reg;
      krc[reg] = mc[reg] / 21;
      owc[reg] = mc[reg] - krc[reg] * 21;
    }
    float bsn[4], alv[4];
    #pragma unroll
    for (int nt = 0; nt < 4; ++nt) { bsn[nt] = b2[nt * 16 + lr]; alv[nt] = a2[nt * 16 + lr]; }

    for (int r = 0; r < 10; ++r) {
      const int posA = (2 * r + krA) * 23 + owA;
      f32x4 acc[4];
      #pragma unroll
      for (int nt = 0; nt < 4; ++nt) acc[nt] = (f32x4){bsn[nt], bsn[nt], bsn[nt], bsn[nt]};
      #pragma unroll
      for (int kh = 0; kh < 3; ++kh)
        #pragma unroll
        for (int kw = 0; kw < 3; ++kw) {
          short8 af = *(const short8*)(pool1b + (posA + kh * 23 + kw) * 40 + 8 * lg);
          #pragma unroll
          for (int nt = 0; nt < 4; ++nt)
            acc[nt] = __builtin_amdgcn_mfma_f32_16x16x32_bf16(af, bfr[kh * 3 + kw][nt], acc[nt], 0, 0, 0);
        }
      #pragma unroll
      for (int nt = 0; nt < 4; ++nt)
        #pragma unroll
        for (int reg = 0; reg < 4; ++reg)
          if (mc[reg] < 63)
            cb2[(krc[reg] * 21 + owc[reg]) * 64 + nt * 16 + lr] =
                __float2bfloat16(prelu(acc[nt][reg], alv[nt]));
      __syncthreads();
      {
        const int ch = t & 63;
        #pragma unroll
        for (int jj = 0; jj < 3; ++jj) {
          int w = (t >> 6) + 4 * jj;
          if (w < 10) {
            float m = -1e30f;
            #pragma unroll
            for (int kh = 0; kh < 3; ++kh)
              #pragma unroll
              for (int kw = 0; kw < 3; ++kw)
                m = fmaxf(m, __bfloat162float(cb2[(kh * 21 + 2 * w + kw) * 64 + ch]));
            // pool2 row r embedded at pool1 byte r*3680 (pool1 rows < 2r are dead)
            *(__hip_bfloat16*)(smemc + r * 3680 + w * 144 + ch * 2) = __float2bfloat16(m);
          }
        }
      }
      __syncthreads();
    }
  }

  // ================= conv3 (3x3x64->64) MFMA + pool3 in registers =================
  {
    __hip_bfloat16* pool3b = (__hip_bfloat16*)(smemc + XB);  // [16][72] (cb2 dead)
    const int nt = wid;
    short8 bfr[9][2];
    #pragma unroll
    for (int khkw = 0; khkw < 9; ++khkw)
      #pragma unroll
      for (int cg = 0; cg < 2; ++cg)
        bfr[khkw][cg] = *(const short8*)(w3t + (((khkw * 2 + cg) * 64 + nt * 16 + lr) * 32 + 8 * lg));
    const float bs = b3[nt * 16 + lr], al = a3[nt * 16 + lr];
    #pragma unroll
    for (int mt = 0; mt < 4; ++mt) {
      const int mA = mt * 16 + lr;
      const int ohA = mA >> 3, owA = mA & 7;
      f32x4 acc = (f32x4){bs, bs, bs, bs};
      #pragma unroll
      for (int kh = 0; kh < 3; ++kh)
        #pragma unroll
        for (int kw = 0; kw < 3; ++kw)
          #pragma unroll
          for (int cg = 0; cg < 2; ++cg) {
            short8 af = *(const short8*)(smemc + (ohA + kh) * 3680 + (owA + kw) * 144 + cg * 64 + lg * 16);
            acc = __builtin_amdgcn_mfma_f32_16x16x32_bf16(af, bfr[kh * 3 + kw][cg], acc, 0, 0, 0);
          }
      // PReLU + 2x2 pool in-register: lg0/lg1 hold row oh=2mt, lg2/lg3 row 2mt+1 (same ow set)
      float v0 = prelu(acc[0], al), v1 = prelu(acc[1], al);
      float v2 = prelu(acc[2], al), v3 = prelu(acc[3], al);
      float h01 = fmaxf(v0, v1), h23 = fmaxf(v2, v3);
      float p01 = fmaxf(h01, __shfl_xor(h01, 32));
      float p23 = fmaxf(h23, __shfl_xor(h23, 32));
      if (lg < 2) {
        pool3b[(mt * 4 + 2 * lg + 0) * 72 + nt * 16 + lr] = __float2bfloat16(p01);
        pool3b[(mt * 4 + 2 * lg + 1) * 72 + nt * 16 + lr] = __float2bfloat16(p23);
      }
    }
  }
  __syncthreads();

  // ================= conv4 (2x2x64->128) MFMA -> vec_g (bf16, permuted flatten) =================
  {
    const __hip_bfloat16* pool3b = (const __hip_bfloat16*)(smemc + XB);
    __hip_bfloat16* vg = vec_g + (size_t)img * 1152;
    int pos = lr < 9 ? lr : 8;
    int hh = pos / 3, wwp = pos - hh * 3;
    short8 afr[8];
    #pragma unroll
    for (int s = 0; s < 8; ++s) {
      int khkw = s >> 1, kh = khkw >> 1, kw = khkw & 1;
      int cb = (s & 1) * 32 + 8 * lg;
      afr[s] = *(const short8*)(pool3b + ((hh + kh) * 4 + (wwp + kw)) * 72 + cb);
    }
    #pragma unroll
    for (int q = 0; q < 2; ++q) {
      int co = (wid * 2 + q) * 16 + lr;
      float bb = b4[co];
      f32x4 acc = (f32x4){bb, bb, bb, bb};
      #pragma unroll
      for (int s = 0; s < 8; ++s) {
        short8 bfr = *(const short8*)(w4t + co * 256 + s * 32 + 8 * lg);
        acc = __builtin_amdgcn_mfma_f32_16x16x32_bf16(afr[s], bfr, acc, 0, 0, 0);
      }
      float al = a4[co];
      #pragma unroll
      for (int reg = 0; reg < 4; ++reg) {
        int pp = 4 * lg + reg;
        if (pp < 9) {
          int h9 = pp / 3, w9 = pp - h9 * 3;
          vg[co * 9 + w9 * 3 + h9] = __float2bfloat16(prelu(acc[reg], al));
        }
      }
    }
  }
}

// ================= kernel 2: dense5 GEMM (M=16 imgs) + heads =================
__global__ __launch_bounds__(256, 2)
void dense_kernel(const __hip_bfloat16* __restrict__ ws,
                  const float* __restrict__ b5, const float* __restrict__ a5,
                  const float* __restrict__ wcls, const float* __restrict__ bcls,
                  const float* __restrict__ wbox, const float* __restrict__ bbox,
                  const float* __restrict__ wpts, const float* __restrict__ bpts,
                  float* __restrict__ out, int nimg)
{
  __shared__ __align__(16) char asm_[16 * 1160 * 2];   // A-tile bf16 [16][1160 pad]
  __shared__ float d5s[16][257];
  __shared__ float zz[16][17];
  const int t = threadIdx.x;
  const int lane = t & 63, wid = t >> 6;
  const int lr = lane & 15, lg = lane >> 4;
  const int blk = blockIdx.x;
  const __hip_bfloat16* w5t = ws + W5T;

  {
    const __hip_bfloat16* src = vec_g + (size_t)blk * 16 * 1152;
    for (int i = t; i < 16 * 144; i += 256) {
      int im = i / 144, kq = i - im * 144;
      *(uint4*)(asm_ + (im * 1160 + kq * 8) * 2) = *(const uint4*)(src + im * 1152 + kq * 8);
    }
  }
  __syncthreads();

  f32x4 acc[4];
  float av[4];
  int jjv[4];
  #pragma unroll
  for (int q = 0; q < 4; ++q) {
    jjv[q] = (wid * 4 + q) * 16 + lr;
    float bv = b5[jjv[q]];
    av[q] = a5[jjv[q]];
    acc[q] = (f32x4){bv, bv, bv, bv};
  }
  for (int ks = 0; ks < 36; ++ks) {
    short8 af = *(const short8*)(asm_ + lr * 2320 + ks * 64 + lg * 16);
    #pragma unroll
    for (int q = 0; q < 4; ++q) {
      short8 bf = *(const short8*)(w5t + jjv[q] * 1152 + ks * 32 + 8 * lg);
      acc[q] = __builtin_amdgcn_mfma_f32_16x16x32_bf16(af, bf, acc[q], 0, 0, 0);
    }
  }
  #pragma unroll
  for (int q = 0; q < 4; ++q)
    #pragma unroll
    for (int reg = 0; reg < 4; ++reg) {
      int im = 4 * lg + reg;
      d5s[im][jjv[q]] = prelu(acc[q][reg], av[q]);
    }
  __syncthreads();

  {
    const int im = t >> 4, o = t & 15;
    float z;
    if (o < 2) {
      z = bcls[o];
      #pragma unroll 4
      for (int k = 0; k < 256; ++k) z += d5s[im][k] * wcls[k * 2 + o];
    } else if (o < 6) {
      z = bbox[o - 2];
      #pragma unroll 4
      for (int k = 0; k < 256; ++k) z += d5s[im][k] * wbox[k * 4 + (o - 2)];
    } else {
      z = bpts[o - 6];
      #pragma unroll 4
      for (int k = 0; k < 256; ++k) z += d5s[im][k] * wpts[k * 10 + (o - 6)];
    }
    zz[im][o] = z;
  }
  __syncthreads();
  {
    const int im = t >> 4, o = t & 15;
    size_t ig = (size_t)blk * 16 + im;
    if (o < 2) {
      float z0 = zz[im][0], z1 = zz[im][1];
      float m = fmaxf(z0, z1);
      float e0 = __expf(z0 - m), e1 = __expf(z1 - m);
      out[ig * 2 + o] = ((o == 0) ? e0 : e1) / (e0 + e1);
    } else if (o < 6) {
      out[(size_t)nimg * 2 + ig * 4 + (o - 2)] = zz[im][o];
    } else {
      out[(size_t)nimg * 6 + ig * 10 + (o - 6)] = zz[im][o];
    }
  }
}

extern "C" void kernel_launch(void* const* d_in, const int* in_sizes, int n_in,
                              void* d_out, int out_size, void* d_ws, size_t ws_size,
                              hipStream_t stream) {
  (void)n_in; (void)out_size; (void)ws_size;
  const float* gin  = (const float*)d_in[0];
  const float* w1   = (const float*)d_in[1];
  const float* b1   = (const float*)d_in[2];
  const float* a1   = (const float*)d_in[3];
  const float* w2   = (const float*)d_in[4];
  const float* b2   = (const float*)d_in[5];
  const float* a2   = (const float*)d_in[6];
  const float* w3   = (const float*)d_in[7];
  const float* b3   = (const float*)d_in[8];
  const float* a3   = (const float*)d_in[9];
  const float* w4   = (const float*)d_in[10];
  const float* b4   = (const float*)d_in[11];
  const float* a4   = (const float*)d_in[12];
  const float* w5   = (const float*)d_in[13];
  const float* b5   = (const float*)d_in[14];
  const float* a5   = (const float*)d_in[15];
  const float* wcls = (const float*)d_in[16];
  const float* bcls = (const float*)d_in[17];
  const float* wbox = (const float*)d_in[18];
  const float* bbox = (const float*)d_in[19];
  const float* wpts = (const float*)d_in[20];
  const float* bpts = (const float*)d_in[21];
  float* out = (float*)d_out;
  __hip_bfloat16* wst = (__hip_bfloat16*)d_ws;
  const int nimg = in_sizes[0] / 6912;   // 4096

  prep_weights<<<(WS_ELEMS + 255) / 256, 256, 0, stream>>>(w1, w2, w3, w4, w5, wst);
  onet_kernel<<<nimg, 256, 0, stream>>>(gin, b1, a1, b2, a2, b3, a3, b4, a4, wst, nimg);
  dense_kernel<<<nimg / 16, 256, 0, stream>>>(wst, b5, a5, wcls, bcls, wbox, bbox,
                                              wpts, bpts, out, nimg);
}

// Round 6
// 741.109 us; speedup vs baseline: 3.8891x; 1.0126x over previous
//
#include <hip/hip_runtime.h>
#include <hip/hip_bf16.h>

typedef __attribute__((ext_vector_type(8))) short short8;   // 8 bf16 (MFMA A/B frag)
typedef __attribute__((ext_vector_type(4))) float f32x4;    // MFMA C/D frag
typedef __attribute__((ext_vector_type(4))) unsigned u32x4;

__device__ __forceinline__ float bf_lo(unsigned v) { return __uint_as_float(v << 16); }
__device__ __forceinline__ float bf_hi(unsigned v) { return __uint_as_float(v & 0xFFFF0000u); }
__device__ __forceinline__ float prelu(float v, float a) { return v >= 0.0f ? v : v * a; }
__device__ __forceinline__ float max3f(float a, float b, float c) { return fmaxf(fmaxf(a, b), c); }

// ---- main-kernel LDS (bytes) ----
// [0, 42320)      pool1 bf16 [529 pos][40 ch]  (pool2 embedded later: row r at byte r*3680, [10 w][72 ch])
// [42320, 53584)  region X: conv1: in2 19 rows x 592 B  |  stage B: cb2 bf16 [3][21][64] (8064 B)
//                 | tail: pool3b bf16 [16][72] (2304 B) + vec stage bf16 [1152] (2304 B)
#define XB   42320
#define SMB  53584          // 3 blocks/CU
#define VSB  (XB + 2304)    // vec staging (after pool3b)

// ---- d_ws layout (bf16 elems) ----
#define W1T 0
#define W2T 1536
#define W3T 19968
#define W4T 56832
#define W5T 89600
#define WS_ELEMS 384512

__device__ __align__(16) __hip_bfloat16 vec_g[4096ull * 1152];   // conv4 output (permuted vec)

__global__ void prep_weights(const float* __restrict__ w1, const float* __restrict__ w2,
                             const float* __restrict__ w3, const float* __restrict__ w4,
                             const float* __restrict__ w5, __hip_bfloat16* __restrict__ ws) {
  int i = blockIdx.x * 256 + threadIdx.x;
  if (i >= WS_ELEMS) return;
  float v = 0.f;
  if (i < W2T) {
    int co = i >> 5, k = i & 31;
    if (k < 27) { int kh = k / 9, r = k % 9, kw = r / 3, ci = r % 3; v = w1[((kh * 3 + kw) * 3 + ci) * 32 + co]; }
  } else if (i < W3T) {
    int j = i - W2T; int khkw = j >> 11, rem = j & 2047, co = rem >> 5, k = rem & 31;
    v = w2[(khkw * 32 + k) * 64 + co];
  } else if (i < W4T) {
    int j = i - W3T; int khkwcg = j >> 11, rem = j & 2047, co = rem >> 5, k = rem & 31;
    v = w3[((khkwcg >> 1) * 64 + (khkwcg & 1) * 32 + k) * 64 + co];
  } else if (i < W5T) {
    int j = i - W4T; int co = j >> 8, k = j & 255; int khkw = k >> 6, ci = k & 63;
    v = w4[(khkw * 64 + ci) * 128 + co];
  } else {
    int j = i - W5T; int jj = j / 1152, k = j - jj * 1152;
    v = w5[k * 256 + jj];
  }
  ws[i] = __float2bfloat16(v);
}

__global__ __launch_bounds__(256, 3)
void onet_kernel(const float* __restrict__ gin,
                 const float* __restrict__ b1, const float* __restrict__ a1,
                 const float* __restrict__ b2, const float* __restrict__ a2,
                 const float* __restrict__ b3, const float* __restrict__ a3,
                 const float* __restrict__ b4, const float* __restrict__ a4,
                 const __hip_bfloat16* __restrict__ ws, int nimg)
{
  __shared__ __align__(16) char smemc[SMB];
  const int t = threadIdx.x;
  const int img = blockIdx.x;
  const int lane = t & 63, wid = t >> 6;
  const int lr = lane & 15, lg = lane >> 4;
  const bool isLg3 = (lg == 3);
  const __hip_bfloat16* w1t = ws + W1T;
  const __hip_bfloat16* w2t = ws + W2T;
  const __hip_bfloat16* w3t = ws + W3T;
  const __hip_bfloat16* w4t = ws + W4T;

  // ================= conv1 (3x3x3->32) MFMA + pool1, 3 input phases =================
  {
    __hip_bfloat16* pool1 = (__hip_bfloat16*)smemc;
    char* in2 = smemc + XB;
    short8 bf1c[2];
    float bias1[2], al1[2];
    #pragma unroll
    for (int n = 0; n < 2; ++n) {
      bf1c[n] = *(const short8*)(w1t + (n * 16 + lr) * 32 + 8 * lg);
      bias1[n] = b1[n * 16 + lr];
      al1[n] = a1[n * 16 + lr];
    }
    const unsigned selc = (lg == 1) ? 0x05040100u : 0x03020100u;
    const unsigned m1c = (lg == 3) ? 0x0000FFFFu : ~0u;
    const unsigned mzc = (lg == 3) ? 0u : ~0u;
    int offv[3][5];
    #pragma unroll
    for (int wt = 0; wt < 3; ++wt) {
      int w = 16 * wt + lr;
      int X[5], KH[5];
      if (lg == 0)      { X[0]=3*w;   X[1]=3*w+2; X[2]=3*w+4; X[3]=3*w+6; X[4]=3*w; KH[0]=0;KH[1]=0;KH[2]=0;KH[3]=0;KH[4]=0; }
      else if (lg == 1) { X[0]=3*w+8; X[1]=3*w+1; X[2]=3*w+3; X[3]=3*w+5; X[4]=3*w; KH[0]=0;KH[1]=1;KH[2]=1;KH[3]=1;KH[4]=1; }
      else if (lg == 2) { X[0]=3*w+7; X[1]=3*w;   X[2]=3*w+2; X[3]=3*w+4; X[4]=3*w; KH[0]=1;KH[1]=2;KH[2]=2;KH[3]=2;KH[4]=2; }
      else              { X[0]=3*w+6; X[1]=3*w+8; X[2]=3*w;   X[3]=3*w;   X[4]=3*w; KH[0]=2;KH[1]=2;KH[2]=2;KH[3]=2;KH[4]=2; }
      #pragma unroll
      for (int i = 0; i < 5; ++i)
        offv[wt][i] = KH[i] * 592 + 2 * X[i] + ((X[i] & 1) ? 294 : 0);
    }

    auto compute_row = [&](int h, int base, float (&cur)[3][2][2]) {
      if (h > 45) {
        #pragma unroll
        for (int wt = 0; wt < 3; ++wt)
          #pragma unroll
          for (int n = 0; n < 2; ++n) { cur[wt][n][0] = -1e30f; cur[wt][n][1] = -1e30f; }
        return;
      }
      const char* rowp = in2 + (h - base) * 592;
      float v[3][2][4];
      #pragma unroll
      for (int wt = 0; wt < 3; ++wt) {
        unsigned r0 = *(const unsigned*)(rowp + offv[wt][0]);
        unsigned r1 = *(const unsigned*)(rowp + offv[wt][1]);
        unsigned r2 = *(const unsigned*)(rowp + offv[wt][2]);
        unsigned r3 = *(const unsigned*)(rowp + offv[wt][3]);
        unsigned r4 = *(const unsigned*)(rowp + offv[wt][4]);
        u32x4 iv = (u32x4){__builtin_amdgcn_perm(r4, r0, selc), r1 & m1c, r2 & mzc, r3 & mzc};
        short8 af = __builtin_bit_cast(short8, iv);
        #pragma unroll
        for (int n = 0; n < 2; ++n) {
          f32x4 acc = (f32x4){bias1[n], bias1[n], bias1[n], bias1[n]};
          acc = __builtin_amdgcn_mfma_f32_16x16x32_bf16(af, bf1c[n], acc, 0, 0, 0);
          #pragma unroll
          for (int reg = 0; reg < 4; ++reg) v[wt][n][reg] = prelu(acc[reg], al1[n]);
        }
      }
      if (isLg3) {
        #pragma unroll
        for (int n = 0; n < 2; ++n) { v[2][n][2] = -1e30f; v[2][n][3] = -1e30f; }
      }
      #pragma unroll
      for (int n = 0; n < 2; ++n) {
        float hd0 = __shfl_down(v[0][n][0], 16);
        float hd1 = __shfl_down(v[1][n][0], 16);
        float hd2 = __shfl_down(v[2][n][0], 16);
        float hx1 = __shfl(v[1][n][0], lr);
        float hx2 = __shfl(v[2][n][0], lr);
        float h0 = isLg3 ? hx1 : hd0;
        float h1 = isLg3 ? hx2 : hd1;
        cur[0][n][0] = max3f(v[0][n][0], v[0][n][1], v[0][n][2]);
        cur[0][n][1] = max3f(v[0][n][2], v[0][n][3], h0);
        cur[1][n][0] = max3f(v[1][n][0], v[1][n][1], v[1][n][2]);
        cur[1][n][1] = max3f(v[1][n][2], v[1][n][3], h1);
        cur[2][n][0] = max3f(v[2][n][0], v[2][n][1], v[2][n][2]);
        cur[2][n][1] = max3f(v[2][n][2], v[2][n][3], hd2);
      }
    };

    auto emit = [&](int r, float (&pa)[3][2][2], float (&pb)[3][2][2], float (&pc)[3][2][2]) {
      #pragma unroll
      for (int wt = 0; wt < 3; ++wt)
        #pragma unroll
        for (int n = 0; n < 2; ++n)
          #pragma unroll
          for (int pp = 0; pp < 2; ++pp) {
            float m = max3f(pa[wt][n][pp], pb[wt][n][pp], pc[wt][n][pp]);
            int pw = 8 * wt + 2 * lg + pp;
            if (pw < 23)
              pool1[(r * 23 + pw) * 40 + n * 16 + lr] = __float2bfloat16(m);
          }
    };

    for (int u = t; u < 95; u += 256) {
      int row = u / 5, q = u - row * 5;
      char* rp = in2 + row * 592;
      if (q < 2)      *(unsigned*)(rp + 288 + 4 * q) = 0u;
      else if (q < 4) *(unsigned*)(rp + 584 + 4 * (q - 2)) = 0u;
      else            *(unsigned short*)(rp + 582) = 0;
    }

    const int base_[3]  = {0, 14, 30};
    const int nrows_[3] = {17, 19, 18};
    const int lo_[3]    = {0, 7, 15};
    const int hi_[3]    = {6, 14, 22};
    for (int ph = 0; ph < 3; ++ph) {
      if (ph) __syncthreads();
      const int base = base_[ph];
      {
        const float* inp = gin + (size_t)img * 6912 + base * 144;
        const int ne = nrows_[ph] * 144;
        for (int i = t; i < ne; i += 256) {
          int rl = i / 144, e = i - rl * 144;
          unsigned short b = __bfloat16_as_ushort(__float2bfloat16(inp[i]));
          char* rp = in2 + rl * 592;
          *(unsigned short*)(rp + 2 * e) = b;
          if (e) *(unsigned short*)(rp + 2 * e + 294) = b;
        }
      }
      __syncthreads();
      int r0 = lo_[ph] + 2 * wid;
      if (r0 <= hi_[ph]) {
        int r1 = (r0 + 1 <= hi_[ph]) ? r0 + 1 : r0;
        float pa[3][2][2], pb[3][2][2], pc[3][2][2];
        compute_row(2 * r0,     base, pa);
        compute_row(2 * r0 + 1, base, pb);
        compute_row(2 * r0 + 2, base, pc);
        emit(r0, pa, pb, pc);
        if (r1 > r0) {
          #pragma unroll
          for (int wt = 0; wt < 3; ++wt)
            #pragma unroll
            for (int n = 0; n < 2; ++n) { pa[wt][n][0] = pc[wt][n][0]; pa[wt][n][1] = pc[wt][n][1]; }
          compute_row(2 * r0 + 3, base, pb);
          compute_row(2 * r0 + 4, base, pc);
          emit(r1, pa, pb, pc);
        }
      }
    }
  }
  __syncthreads();

  // ================= stage B: conv2 (3x3x32->64) MFMA + pool2 (embedded in pool1) =================
  {
    const __hip_bfloat16* pool1b = (const __hip_bfloat16*)smemc;
    __hip_bfloat16* cb2 = (__hip_bfloat16*)(smemc + XB);     // [3][21][64]
    const int wv = wid;
    short8 bfr[9][4];
    #pragma unroll
    for (int khkw = 0; khkw < 9; ++khkw)
      #pragma unroll
      for (int nt = 0; nt < 4; ++nt)
        bfr[khkw][nt] = *(const short8*)(w2t + ((khkw * 64 + nt * 16 + lr) * 32 + 8 * lg));
    int mA = wv * 16 + lr; if (mA > 62) mA = 62;
    const int krA = mA / 21, owA = mA - krA * 21;
    int mc[4], krc[4], owc[4];
    #pragma unroll
    for (int reg = 0; reg < 4; ++reg) {
      mc[reg] = wv * 16 + lg * 4 + reg;
      krc[reg] = mc[reg] / 21;
      owc[reg] = mc[reg] - krc[reg] * 21;
    }
    float bsn[4], alv[4];
    #pragma unroll
    for (int nt = 0; nt < 4; ++nt) { bsn[nt] = b2[nt * 16 + lr]; alv[nt] = a2[nt * 16 + lr]; }

    for (int r = 0; r < 10; ++r) {
      const int posA = (2 * r + krA) * 23 + owA;
      f32x4 acc[4];
      #pragma unroll
      for (int nt = 0; nt < 4; ++nt) acc[nt] = (f32x4){bsn[nt], bsn[nt], bsn[nt], bsn[nt]};
      #pragma unroll
      for (int kh = 0; kh < 3; ++kh)
        #pragma unroll
        for (int kw = 0; kw < 3; ++kw) {
          short8 af = *(const short8*)(pool1b + (posA + kh * 23 + kw) * 40 + 8 * lg);
          #pragma unroll
          for (int nt = 0; nt < 4; ++nt)
            acc[nt] = __builtin_amdgcn_mfma_f32_16x16x32_bf16(af, bfr[kh * 3 + kw][nt], acc[nt], 0, 0, 0);
        }
      #pragma unroll
      for (int nt = 0; nt < 4; ++nt)
        #pragma unroll
        for (int reg = 0; reg < 4; ++reg)
          if (mc[reg] < 63)
            cb2[(krc[reg] * 21 + owc[reg]) * 64 + nt * 16 + lr] =
                __float2bfloat16(prelu(acc[nt][reg], alv[nt]));
      __syncthreads();
      {
        const int ch = t & 63;
        #pragma unroll
        for (int jj = 0; jj < 3; ++jj) {
          int w = (t >> 6) + 4 * jj;
          if (w < 10) {
            float m = -1e30f;
            #pragma unroll
            for (int kh = 0; kh < 3; ++kh)
              #pragma unroll
              for (int kw = 0; kw < 3; ++kw)
                m = fmaxf(m, __bfloat162float(cb2[(kh * 21 + 2 * w + kw) * 64 + ch]));
            *(__hip_bfloat16*)(smemc + r * 3680 + w * 144 + ch * 2) = __float2bfloat16(m);
          }
        }
      }
      __syncthreads();
    }
  }

  // ================= conv3 (3x3x64->64) MFMA + pool3 in registers =================
  {
    __hip_bfloat16* pool3b = (__hip_bfloat16*)(smemc + XB);  // [16][72]
    const int nt = wid;
    short8 bfr[9][2];
    #pragma unroll
    for (int khkw = 0; khkw < 9; ++khkw)
      #pragma unroll
      for (int cg = 0; cg < 2; ++cg)
        bfr[khkw][cg] = *(const short8*)(w3t + (((khkw * 2 + cg) * 64 + nt * 16 + lr) * 32 + 8 * lg));
    const float bs = b3[nt * 16 + lr], al = a3[nt * 16 + lr];
    #pragma unroll
    for (int mt = 0; mt < 4; ++mt) {
      const int mA = mt * 16 + lr;
      const int ohA = mA >> 3, owA = mA & 7;
      f32x4 acc = (f32x4){bs, bs, bs, bs};
      #pragma unroll
      for (int kh = 0; kh < 3; ++kh)
        #pragma unroll
        for (int kw = 0; kw < 3; ++kw)
          #pragma unroll
          for (int cg = 0; cg < 2; ++cg) {
            short8 af = *(const short8*)(smemc + (ohA + kh) * 3680 + (owA + kw) * 144 + cg * 64 + lg * 16);
            acc = __builtin_amdgcn_mfma_f32_16x16x32_bf16(af, bfr[kh * 3 + kw][cg], acc, 0, 0, 0);
          }
      float v0 = prelu(acc[0], al), v1 = prelu(acc[1], al);
      float v2 = prelu(acc[2], al), v3 = prelu(acc[3], al);
      float h01 = fmaxf(v0, v1), h23 = fmaxf(v2, v3);
      float p01 = fmaxf(h01, __shfl_xor(h01, 32));
      float p23 = fmaxf(h23, __shfl_xor(h23, 32));
      if (lg < 2) {
        pool3b[(mt * 4 + 2 * lg + 0) * 72 + nt * 16 + lr] = __float2bfloat16(p01);
        pool3b[(mt * 4 + 2 * lg + 1) * 72 + nt * 16 + lr] = __float2bfloat16(p23);
      }
    }
  }
  __syncthreads();

  // ================= conv4 (2x2x64->128) MFMA -> LDS vec stage -> coalesced global =================
  {
    const __hip_bfloat16* pool3b = (const __hip_bfloat16*)(smemc + XB);
    __hip_bfloat16* vecs = (__hip_bfloat16*)(smemc + VSB);   // [1152]
    int pos = lr < 9 ? lr : 8;
    int hh = pos / 3, wwp = pos - hh * 3;
    short8 afr[8];
    #pragma unroll
    for (int s = 0; s < 8; ++s) {
      int khkw = s >> 1, kh = khkw >> 1, kw = khkw & 1;
      int cb = (s & 1) * 32 + 8 * lg;
      afr[s] = *(const short8*)(pool3b + ((hh + kh) * 4 + (wwp + kw)) * 72 + cb);
    }
    #pragma unroll
    for (int q = 0; q < 2; ++q) {
      int co = (wid * 2 + q) * 16 + lr;
      float bb = b4[co];
      f32x4 acc = (f32x4){bb, bb, bb, bb};
      #pragma unroll
      for (int s = 0; s < 8; ++s) {
        short8 bfr = *(const short8*)(w4t + co * 256 + s * 32 + 8 * lg);
        acc = __builtin_amdgcn_mfma_f32_16x16x32_bf16(afr[s], bfr, acc, 0, 0, 0);
      }
      float al = a4[co];
      #pragma unroll
      for (int reg = 0; reg < 4; ++reg) {
        int pp = 4 * lg + reg;
        if (pp < 9) {
          int h9 = pp / 3, w9 = pp - h9 * 3;
          vecs[co * 9 + w9 * 3 + h9] = __float2bfloat16(prelu(acc[reg], al));
        }
      }
    }
  }
  __syncthreads();
  {
    // coalesced 16B stores: 144 x uint4 = 2304 B contiguous per image
    const __hip_bfloat16* vecs = (const __hip_bfloat16*)(smemc + VSB);
    __hip_bfloat16* vg = vec_g + (size_t)img * 1152;
    if (t < 144)
      *(uint4*)(vg + t * 8) = *(const uint4*)(vecs + t * 8);
  }
}

// ================= kernel 2: dense5 GEMM (M=16 imgs) + heads =================
__global__ __launch_bounds__(256, 2)
void dense_kernel(const __hip_bfloat16* __restrict__ ws,
                  const float* __restrict__ b5, const float* __restrict__ a5,
                  const float* __restrict__ wcls, const float* __restrict__ bcls,
                  const float* __restrict__ wbox, const float* __restrict__ bbox,
                  const float* __restrict__ wpts, const float* __restrict__ bpts,
                  float* __restrict__ out, int nimg)
{
  __shared__ __align__(16) char asm_[16 * 1160 * 2];   // A-tile bf16 [16][1160 pad]
  __shared__ float d5s[16][257];
  __shared__ float zz[16][17];
  const int t = threadIdx.x;
  const int lane = t & 63, wid = t >> 6;
  const int lr = lane & 15, lg = lane >> 4;
  const int blk = blockIdx.x;
  const __hip_bfloat16* w5t = ws + W5T;

  {
    const __hip_bfloat16* src = vec_g + (size_t)blk * 16 * 1152;
    for (int i = t; i < 16 * 144; i += 256) {
      int im = i / 144, kq = i - im * 144;
      *(uint4*)(asm_ + (im * 1160 + kq * 8) * 2) = *(const uint4*)(src + im * 1152 + kq * 8);
    }
  }
  __syncthreads();

  f32x4 acc[4];
  float av[4];
  int jjv[4];
  #pragma unroll
  for (int q = 0; q < 4; ++q) {
    jjv[q] = (wid * 4 + q) * 16 + lr;
    float bv = b5[jjv[q]];
    av[q] = a5[jjv[q]];
    acc[q] = (f32x4){bv, bv, bv, bv};
  }
  for (int ks = 0; ks < 36; ++ks) {
    short8 af = *(const short8*)(asm_ + lr * 2320 + ks * 64 + lg * 16);
    #pragma unroll
    for (int q = 0; q < 4; ++q) {
      short8 bf = *(const short8*)(w5t + jjv[q] * 1152 + ks * 32 + 8 * lg);
      acc[q] = __builtin_amdgcn_mfma_f32_16x16x32_bf16(af, bf, acc[q], 0, 0, 0);
    }
  }
  #pragma unroll
  for (int q = 0; q < 4; ++q)
    #pragma unroll
    for (int reg = 0; reg < 4; ++reg) {
      int im = 4 * lg + reg;
      d5s[im][jjv[q]] = prelu(acc[q][reg], av[q]);
    }
  __syncthreads();

  {
    const int im = t >> 4, o = t & 15;
    float z;
    if (o < 2) {
      z = bcls[o];
      #pragma unroll 4
      for (int k = 0; k < 256; ++k) z += d5s[im][k] * wcls[k * 2 + o];
    } else if (o < 6) {
      z = bbox[o - 2];
      #pragma unroll 4
      for (int k = 0; k < 256; ++k) z += d5s[im][k] * wbox[k * 4 + (o - 2)];
    } else {
      z = bpts[o - 6];
      #pragma unroll 4
      for (int k = 0; k < 256; ++k) z += d5s[im][k] * wpts[k * 10 + (o - 6)];
    }
    zz[im][o] = z;
  }
  __syncthreads();
  {
    const int im = t >> 4, o = t & 15;
    size_t ig = (size_t)blk * 16 + im;
    if (o < 2) {
      float z0 = zz[im][0], z1 = zz[im][1];
      float m = fmaxf(z0, z1);
      float e0 = __expf(z0 - m), e1 = __expf(z1 - m);
      out[ig * 2 + o] = ((o == 0) ? e0 : e1) / (e0 + e1);
    } else if (o < 6) {
      out[(size_t)nimg * 2 + ig * 4 + (o - 2)] = zz[im][o];
    } else {
      out[(size_t)nimg * 6 + ig * 10 + (o - 6)] = zz[im][o];
    }
  }
}

extern "C" void kernel_launch(void* const* d_in, const int* in_sizes, int n_in,
                              void* d_out, int out_size, void* d_ws, size_t ws_size,
                              hipStream_t stream) {
  (void)n_in; (void)out_size; (void)ws_size;
  const float* gin  = (const float*)d_in[0];
  const float* w1   = (const float*)d_in[1];
  const float* b1   = (const float*)d_in[2];
  const float* a1   = (const float*)d_in[3];
  const float* w2   = (const float*)d_in[4];
  const float* b2   = (const float*)d_in[5];
  const float* a2   = (const float*)d_in[6];
  const float* w3   = (const float*)d_in[7];
  const float* b3   = (const float*)d_in[8];
  const float* a3   = (const float*)d_in[9];
  const float* w4   = (const float*)d_in[10];
  const float* b4   = (const float*)d_in[11];
  const float* a4   = (const float*)d_in[12];
  const float* w5   = (const float*)d_in[13];
  const float* b5   = (const float*)d_in[14];
  const float* a5   = (const float*)d_in[15];
  const float* wcls = (const float*)d_in[16];
  const float* bcls = (const float*)d_in[17];
  const float* wbox = (const float*)d_in[18];
  const float* bbox = (const float*)d_in[19];
  const float* wpts = (const float*)d_in[20];
  const float* bpts = (const float*)d_in[21];
  float* out = (float*)d_out;
  __hip_bfloat16* wst = (__hip_bfloat16*)d_ws;
  const int nimg = in_sizes[0] / 6912;   // 4096

  prep_weights<<<(WS_ELEMS + 255) / 256, 256, 0, stream>>>(w1, w2, w3, w4, w5, wst);
  onet_kernel<<<nimg, 256, 0, stream>>>(gin, b1, a1, b2, a2, b3, a3, b4, a4, wst, nimg);
  dense_kernel<<<nimg / 16, 256, 0, stream>>>(wst, b5, a5, wcls, bcls, wbox, bbox,
                                              wpts, bpts, out, nimg);
}